// Round 3
// baseline (1742.557 us; speedup 1.0000x reference)
//
#include <hip/hip_runtime.h>

constexpr int N_NODES = 100000;
constexpr int N_EDGES = 1600000;
constexpr int CHUNK_E = N_EDGES / 8;   // 200000

// ---------------- graph preprocessing ----------------

__global__ void hist8_kernel(const int* __restrict__ ei, int* __restrict__ deg8,
                             int* __restrict__ cnt8) {
    int c = blockIdx.x & 7;
    int lb = blockIdx.x >> 3;
    int* dg = deg8 + c * N_NODES;
    int* ct = cnt8 + c * N_NODES;
    int e_end = (c + 1) * CHUNK_E;
    for (int e = c * CHUNK_E + lb * 256 + threadIdx.x; e < e_end; e += 256 * 256) {
        int s = ei[e];
        int d = ei[N_EDGES + e];
        atomicAdd(&dg[s], 1);
        atomicAdd(&ct[d], 1);
    }
}

__global__ void scan1_kernel(const int* __restrict__ cnt8, const int* __restrict__ deg8,
                             int* __restrict__ rp, int* __restrict__ bsum,
                             float* __restrict__ dis) {
    __shared__ int sm[256];
    int i = blockIdx.x * 256 + threadIdx.x;
    int v = 0;
    if (i < N_NODES) {
        int dv = 0;
#pragma unroll
        for (int c = 0; c < 8; ++c) {
            v += cnt8[c * N_NODES + i];
            dv += deg8[c * N_NODES + i];
        }
        dis[i] = dv > 0 ? rsqrtf((float)dv) : 0.f;
    }
    sm[threadIdx.x] = v;
    __syncthreads();
    for (int off = 1; off < 256; off <<= 1) {
        int t = (threadIdx.x >= off) ? sm[threadIdx.x - off] : 0;
        __syncthreads();
        sm[threadIdx.x] += t;
        __syncthreads();
    }
    if (i < N_NODES) rp[i] = sm[threadIdx.x] - v;
    if (threadIdx.x == 255) bsum[blockIdx.x] = sm[255];
}

__global__ void scan2_kernel(int* __restrict__ bsum, int nb) {
    __shared__ int sm[512];
    int t = threadIdx.x;
    int v = (t < nb) ? bsum[t] : 0;
    sm[t] = v;
    __syncthreads();
    for (int off = 1; off < 512; off <<= 1) {
        int u = (t >= off) ? sm[t - off] : 0;
        __syncthreads();
        sm[t] += u;
        __syncthreads();
    }
    if (t < nb) bsum[t] = sm[t] - v;
}

__global__ void scan3_kernel(int* __restrict__ rp, const int* __restrict__ bsum,
                             const int* __restrict__ cnt8, int* __restrict__ rp8) {
    int i = blockIdx.x * 256 + threadIdx.x;
    if (i < N_NODES) {
        int base = rp[i] + bsum[blockIdx.x];
        rp[i] = base;
        int run = base;
#pragma unroll
        for (int c = 0; c < 8; ++c) {
            rp8[c * N_NODES + i] = run;
            run += cnt8[c * N_NODES + i];
        }
    }
    if (i == 0) rp[N_NODES] = N_EDGES;
}

__global__ void fill8_kernel(const int* __restrict__ ei, const int* __restrict__ rp8,
                             int* __restrict__ cur8, const float* __restrict__ dis,
                             int2* __restrict__ csrw) {
    int c = blockIdx.x & 7;
    int lb = blockIdx.x >> 3;
    const int* r8 = rp8 + c * N_NODES;
    int* cu = cur8 + c * N_NODES;
    int e_end = (c + 1) * CHUNK_E;
    for (int e = c * CHUNK_E + lb * 256 + threadIdx.x; e < e_end; e += 256 * 256) {
        int s = ei[e];
        int d = ei[N_EDGES + e];
        int pos = r8[d] + atomicAdd(&cu[d], 1);
        csrw[pos] = make_int2(s, __float_as_int(-dis[s] * dis[d]));
    }
}

// ---------------- fused Clenshaw step ----------------
// OUT[row] = SCALE * sum_j w_j*IN[src_j] + A'[row]@W - (HAS_B2 ? B2[row] : 0)
// A' = BN_A ? relu(ss*A+sh) : A.  FUSE_STATS: per-block column sum/sumsq partials.

template <int FI, int SCALE, bool HAS_B2, bool BN_A, bool FUSE_STATS>
__global__ __launch_bounds__(256) void cheb_step_kernel(
    const int* __restrict__ rp, const int2* __restrict__ csrw,
    const float* __restrict__ IN, const float* __restrict__ B2,
    const float* __restrict__ A, const float* __restrict__ W,
    const float* __restrict__ ss, float* __restrict__ OUT,
    float* __restrict__ partials) {
    __shared__ float Wl[FI * 36];
    __shared__ float Atile[28][FI + 1];
    __shared__ float ls[72];
    int tid = threadIdx.x;                       // 252 threads
    for (int i = tid; i < FI * 36; i += 252) Wl[i] = W[i];
    int r0 = blockIdx.x * 28;
    for (int i = tid; i < 28 * FI; i += 252) {
        int r = i / FI, f = i % FI;
        int row = r0 + r;
        float v = (row < N_NODES) ? A[row * FI + f] : 0.f;
        if (BN_A) v = fmaxf(fmaf(ss[f], v, ss[36 + f]), 0.f);
        Atile[r][f] = v;
    }
    if (FUSE_STATS && tid < 72) ls[tid] = 0.f;
    __syncthreads();
    int r = tid / 9, c = tid % 9;
    int row = r0 + r;
    bool valid = row < N_NODES;
    float gx = 0, gy = 0, gz = 0, gw = 0;
    if (valid) {
        int beg = rp[row], end = rp[row + 1];
        const float4* IN4 = (const float4*)IN;
        for (int j = beg; j < end; ++j) {
            int2 e = csrw[j];
            float w = __int_as_float(e.y);
            float4 v = IN4[e.x * 9 + c];
            gx = fmaf(w, v.x, gx); gy = fmaf(w, v.y, gy);
            gz = fmaf(w, v.z, gz); gw = fmaf(w, v.w, gw);
        }
    }
    float px = 0, py = 0, pz = 0, pw = 0;
    const float4* Wl4 = (const float4*)Wl;
#pragma unroll 4
    for (int f = 0; f < FI; ++f) {
        float a = Atile[r][f];
        float4 wv = Wl4[f * 9 + c];
        px = fmaf(a, wv.x, px); py = fmaf(a, wv.y, py);
        pz = fmaf(a, wv.z, pz); pw = fmaf(a, wv.w, pw);
    }
    const float S = (float)SCALE;
    float4 o;
    o.x = fmaf(S, gx, px); o.y = fmaf(S, gy, py);
    o.z = fmaf(S, gz, pz); o.w = fmaf(S, gw, pw);
    if (valid) {
        if (HAS_B2) {
            float4 b = ((const float4*)B2)[row * 9 + c];
            o.x -= b.x; o.y -= b.y; o.z -= b.z; o.w -= b.w;
        }
        ((float4*)OUT)[row * 9 + c] = o;
        if (FUSE_STATS) {
            atomicAdd(&ls[c * 4 + 0], o.x); atomicAdd(&ls[36 + c * 4 + 0], o.x * o.x);
            atomicAdd(&ls[c * 4 + 1], o.y); atomicAdd(&ls[36 + c * 4 + 1], o.y * o.y);
            atomicAdd(&ls[c * 4 + 2], o.z); atomicAdd(&ls[36 + c * 4 + 2], o.z * o.z);
            atomicAdd(&ls[c * 4 + 3], o.w); atomicAdd(&ls[36 + c * 4 + 3], o.w * o.w);
        }
    }
    if (FUSE_STATS) {
        __syncthreads();
        if (tid < 72) partials[blockIdx.x * 72 + tid] = ls[tid];
    }
}

// ---------------- initial projection: C[N,36] = A'[N,FI] @ W ----------------

template <int FI, bool BN_A>
__global__ __launch_bounds__(256) void proj_kernel(
    const float* __restrict__ A, const float* __restrict__ W,
    const float* __restrict__ ss, float* __restrict__ C) {
    __shared__ float Wl[FI * 36];
    __shared__ float Al[64][FI + 1];
    int tid = threadIdx.x;
    for (int i = tid; i < FI * 36; i += 256) Wl[i] = W[i];
    int r0 = blockIdx.x * 64;
    for (int i = tid; i < 64 * FI; i += 256) {
        int r = i / FI, f = i % FI;
        int row = r0 + r;
        float v = (row < N_NODES) ? A[row * FI + f] : 0.f;
        if (BN_A) v = fmaxf(fmaf(ss[f], v, ss[36 + f]), 0.f);
        Al[r][f] = v;
    }
    __syncthreads();
    int r = tid >> 2, q = tid & 3;
    int row = r0 + r;
    if (row >= N_NODES) return;
    float acc[9] = {};
#pragma unroll 4
    for (int f = 0; f < FI; ++f) {
        float a = Al[r][f];
#pragma unroll
        for (int j = 0; j < 9; ++j)
            acc[j] = fmaf(a, Wl[f * 36 + q * 9 + j], acc[j]);
    }
#pragma unroll
    for (int j = 0; j < 9; ++j) C[row * 36 + q * 9 + j] = acc[j];
}

// ---------------- GIN mega-kernel ----------------
// OUT[row] = relu( relu( (x[row]+sum x[src]) @ w1 + b1 ) @ w2 + b2 ), + stats partials

__global__ __launch_bounds__(256) void gin_fused_kernel(
    const int* __restrict__ rp, const int2* __restrict__ csrw,
    const float* __restrict__ X, const float* __restrict__ w1,
    const float* __restrict__ b1, const float* __restrict__ w2,
    const float* __restrict__ b2, float* __restrict__ OUT,
    float* __restrict__ partials) {
    __shared__ float W1l[64 * 36];
    __shared__ float W2l[36 * 36];
    __shared__ float B1l[36], B2l[36];
    __shared__ float Ht[16][68];
    __shared__ float M1t[16][40];
    __shared__ float ls[72];
    int tid = threadIdx.x;                       // 256 = 16 rows x 16 lanes
    for (int i = tid; i < 64 * 36; i += 256) W1l[i] = w1[i];
    for (int i = tid; i < 36 * 36; i += 256) W2l[i] = w2[i];
    if (tid < 36) { B1l[tid] = b1[tid]; B2l[tid] = b2[tid]; }
    if (tid < 72) ls[tid] = 0.f;
    int r = tid >> 4, l = tid & 15;
    int row = blockIdx.x * 16 + r;
    bool valid = row < N_NODES;
    float4 h = {0.f, 0.f, 0.f, 0.f};
    if (valid) {
        const float4* X4 = (const float4*)X;
        h = X4[row * 16 + l];
        int beg = rp[row], end = rp[row + 1];
        for (int j = beg; j < end; ++j) {
            int2 e = csrw[j];
            float4 v = X4[e.x * 16 + l];
            h.x += v.x; h.y += v.y; h.z += v.z; h.w += v.w;
        }
    }
    Ht[r][l * 4 + 0] = h.x; Ht[r][l * 4 + 1] = h.y;
    Ht[r][l * 4 + 2] = h.z; Ht[r][l * 4 + 3] = h.w;
    __syncthreads();
    // M1: lane l -> cols l, l+16, (l<4: l+32)
    float m1a = B1l[l], m1b = B1l[l + 16], m1c = (l < 4) ? B1l[l + 32] : 0.f;
#pragma unroll 4
    for (int f = 0; f < 64; ++f) {
        float a = Ht[r][f];
        m1a = fmaf(a, W1l[f * 36 + l], m1a);
        m1b = fmaf(a, W1l[f * 36 + l + 16], m1b);
        if (l < 4) m1c = fmaf(a, W1l[f * 36 + l + 32], m1c);
    }
    m1a = fmaxf(m1a, 0.f); m1b = fmaxf(m1b, 0.f); m1c = fmaxf(m1c, 0.f);
    M1t[r][l] = m1a; M1t[r][l + 16] = m1b;
    if (l < 4) M1t[r][l + 32] = m1c;
    __syncthreads();
    float m2a = B2l[l], m2b = B2l[l + 16], m2c = (l < 4) ? B2l[l + 32] : 0.f;
#pragma unroll 4
    for (int f = 0; f < 36; ++f) {
        float a = M1t[r][f];
        m2a = fmaf(a, W2l[f * 36 + l], m2a);
        m2b = fmaf(a, W2l[f * 36 + l + 16], m2b);
        if (l < 4) m2c = fmaf(a, W2l[f * 36 + l + 32], m2c);
    }
    m2a = fmaxf(m2a, 0.f); m2b = fmaxf(m2b, 0.f); m2c = fmaxf(m2c, 0.f);
    if (valid) {
        OUT[row * 36 + l] = m2a;
        OUT[row * 36 + l + 16] = m2b;
        if (l < 4) OUT[row * 36 + l + 32] = m2c;
        atomicAdd(&ls[l], m2a); atomicAdd(&ls[36 + l], m2a * m2a);
        atomicAdd(&ls[l + 16], m2b); atomicAdd(&ls[36 + l + 16], m2b * m2b);
        if (l < 4) { atomicAdd(&ls[l + 32], m2c); atomicAdd(&ls[36 + l + 32], m2c * m2c); }
    }
    __syncthreads();
    if (tid < 72) partials[blockIdx.x * 72 + tid] = ls[tid];
}

// ---------------- finalize: reduce partials -> BN scale/shift ----------------

__global__ __launch_bounds__(1024) void finalize_kernel(
    const float* __restrict__ partials, int nb, const float* __restrict__ g,
    const float* __restrict__ be, float* __restrict__ ss) {
    __shared__ float red[14][72];
    __shared__ float tot[72];
    int tid = threadIdx.x;                       // 1008 = 14 x 72
    int grp = tid / 72, c = tid % 72;
    float s = 0.f;
    for (int i = grp; i < nb; i += 14) s += partials[i * 72 + c];
    red[grp][c] = s;
    __syncthreads();
    if (grp == 0) {
        float t = 0.f;
#pragma unroll
        for (int k = 0; k < 14; ++k) t += red[k][c];
        tot[c] = t;
    }
    __syncthreads();
    if (tid < 36) {
        float m = tot[tid] / (float)N_NODES;
        float v = tot[36 + tid] / (float)N_NODES - m * m;
        float sc = g[tid] * rsqrtf(v + 1e-5f);
        ss[tid] = sc;
        ss[36 + tid] = be[tid] - m * sc;
    }
}

// ---------------- final concat GEMM with BN folds ----------------

__global__ __launch_bounds__(256) void fused3_kernel(
    const float* __restrict__ X1, const float* __restrict__ ssA,
    const float* __restrict__ X2, const float* __restrict__ ssB,
    const float* __restrict__ X3, const float* __restrict__ ssC,
    const float* __restrict__ W, const float* __restrict__ b,
    float* __restrict__ out) {
    __shared__ float Wl[108 * 32];
    __shared__ float Al[64][109];
    int tid = threadIdx.x;
    for (int i = tid; i < 108 * 32; i += 256) Wl[i] = W[i];
    int r0 = blockIdx.x * 64;
    for (int i = tid; i < 64 * 108; i += 256) {
        int r = i / 108, f = i % 108;
        int row = r0 + r;
        float v = 0.f;
        if (row < N_NODES) {
            if (f < 36) {
                v = fmaxf(fmaf(ssA[f], X1[row * 36 + f], ssA[36 + f]), 0.f);
            } else if (f < 72) {
                int ff = f - 36;
                v = fmaxf(fmaf(ssB[ff], X2[row * 36 + ff], ssB[36 + ff]), 0.f);
            } else {
                int ff = f - 72;
                v = fmaf(ssC[ff], X3[row * 36 + ff], ssC[36 + ff]);
            }
        }
        Al[r][f] = v;
    }
    __syncthreads();
    int r = tid >> 2, q = tid & 3;
    int row = r0 + r;
    if (row >= N_NODES) return;
    float acc[8];
#pragma unroll
    for (int j = 0; j < 8; ++j) acc[j] = b[q * 8 + j];
    for (int f = 0; f < 108; ++f) {
        float a = Al[r][f];
#pragma unroll
        for (int j = 0; j < 8; ++j)
            acc[j] = fmaf(a, Wl[f * 32 + q * 8 + j], acc[j]);
    }
#pragma unroll
    for (int j = 0; j < 8; ++j) out[row * 32 + q * 8 + j] = acc[j];
}

// ---------------- launch ----------------

extern "C" void kernel_launch(void* const* d_in, const int* in_sizes, int n_in,
                              void* d_out, int out_size, void* d_ws, size_t ws_size,
                              hipStream_t stream) {
    const float* x      = (const float*)d_in[0];
    const int*   ei     = (const int*)d_in[1];
    const float* W1_1   = (const float*)d_in[2];
    // b1_1 / b1_2 cancel exactly under training-mode BN -> dropped.
    const float* g1_1   = (const float*)d_in[4];
    const float* be1_1  = (const float*)d_in[5];
    const float* W1_2   = (const float*)d_in[6];
    const float* g1_2   = (const float*)d_in[8];
    const float* be1_2  = (const float*)d_in[9];
    const float* gin_w1 = (const float*)d_in[10];
    const float* gin_b1 = (const float*)d_in[11];
    const float* gin_w2 = (const float*)d_in[12];
    const float* gin_b2 = (const float*)d_in[13];
    const float* g2     = (const float*)d_in[14];
    const float* be2    = (const float*)d_in[15];
    const float* W4     = (const float*)d_in[16];
    const float* b4     = (const float*)d_in[17];
    float* out = (float*)d_out;

    char* ws = (char*)d_ws;
    size_t off = 0;
    auto alloc = [&](size_t bytes) -> char* {
        char* p = ws + off;
        off = (off + bytes + 255) & ~(size_t)255;
        return p;
    };
    int*   cnt8  = (int*)alloc((size_t)8 * N_NODES * 4);
    int*   deg8  = (int*)alloc((size_t)8 * N_NODES * 4);   // reused as cur8
    size_t zend = off;
    int*   rp    = (int*)alloc((size_t)(N_NODES + 1) * 4);
    int*   rp8   = (int*)alloc((size_t)8 * N_NODES * 4);
    int*   bsum  = (int*)alloc(512 * 4);
    float* dis   = (float*)alloc((size_t)N_NODES * 4);
    int2*  csrw  = (int2*)alloc((size_t)N_EDGES * 8);
    float* ssA   = (float*)alloc(72 * 4);
    float* ssB   = (float*)alloc(72 * 4);
    float* ssC   = (float*)alloc(72 * 4);
    float* partials = (float*)alloc((size_t)6250 * 72 * 4);
    constexpr size_t NB36 = (size_t)N_NODES * 36 * 4;
    float* R0 = (float*)alloc(NB36);
    float* R1 = (float*)alloc(NB36);
    float* R2 = (float*)alloc(NB36);
    float* X1 = (float*)alloc(NB36);
    float* X2 = (float*)alloc(NB36);
    float* X3 = (float*)alloc(NB36);
    if (off > ws_size) return;

    hipMemsetAsync(d_ws, 0, zend, stream);

    const int SCAN_BLKS = (N_NODES + 255) / 256;      // 391
    hist8_kernel<<<2048, 256, 0, stream>>>(ei, deg8, cnt8);
    scan1_kernel<<<SCAN_BLKS, 256, 0, stream>>>(cnt8, deg8, rp, bsum, dis);
    scan2_kernel<<<1, 512, 0, stream>>>(bsum, SCAN_BLKS);
    scan3_kernel<<<SCAN_BLKS, 256, 0, stream>>>(rp, bsum, cnt8, rp8);
    hipMemsetAsync(deg8, 0, (size_t)8 * N_NODES * 4, stream);
    fill8_kernel<<<2048, 256, 0, stream>>>(ei, rp8, deg8, dis, csrw);

    const int PROJ_BLKS = (N_NODES + 63) / 64;        // 1563
    const int STEP_BLKS = (N_NODES + 27) / 28;        // 3572
    const int GIN_BLKS  = (N_NODES + 15) / 16;        // 6250

    // ---- conv1_1 (Clenshaw, FI=64, A=x, no BN on A) ----
    proj_kernel<64, false><<<PROJ_BLKS, 256, 0, stream>>>(x, W1_1 + 7 * 2304, nullptr, R0);
    cheb_step_kernel<64, 2, false, false, false><<<STEP_BLKS, 252, 0, stream>>>(
        rp, csrw, R0, nullptr, x, W1_1 + 6 * 2304, nullptr, R1, nullptr);
    cheb_step_kernel<64, 2, true, false, false><<<STEP_BLKS, 252, 0, stream>>>(
        rp, csrw, R1, R0, x, W1_1 + 5 * 2304, nullptr, R2, nullptr);
    cheb_step_kernel<64, 2, true, false, false><<<STEP_BLKS, 252, 0, stream>>>(
        rp, csrw, R2, R1, x, W1_1 + 4 * 2304, nullptr, R0, nullptr);
    cheb_step_kernel<64, 2, true, false, false><<<STEP_BLKS, 252, 0, stream>>>(
        rp, csrw, R0, R2, x, W1_1 + 3 * 2304, nullptr, R1, nullptr);
    cheb_step_kernel<64, 2, true, false, false><<<STEP_BLKS, 252, 0, stream>>>(
        rp, csrw, R1, R0, x, W1_1 + 2 * 2304, nullptr, R2, nullptr);
    cheb_step_kernel<64, 2, true, false, false><<<STEP_BLKS, 252, 0, stream>>>(
        rp, csrw, R2, R1, x, W1_1 + 1 * 2304, nullptr, R0, nullptr);
    cheb_step_kernel<64, 1, true, false, true><<<STEP_BLKS, 252, 0, stream>>>(
        rp, csrw, R0, R2, x, W1_1 + 0 * 2304, nullptr, X1, partials);
    finalize_kernel<<<1, 1008, 0, stream>>>(partials, STEP_BLKS, g1_1, be1_1, ssA);

    // ---- conv1_2 (Clenshaw, FI=36, A=X1 with BN ssA) ----
    proj_kernel<36, true><<<PROJ_BLKS, 256, 0, stream>>>(X1, W1_2 + 7 * 1296, ssA, R0);
    cheb_step_kernel<36, 2, false, true, false><<<STEP_BLKS, 252, 0, stream>>>(
        rp, csrw, R0, nullptr, X1, W1_2 + 6 * 1296, ssA, R1, nullptr);
    cheb_step_kernel<36, 2, true, true, false><<<STEP_BLKS, 252, 0, stream>>>(
        rp, csrw, R1, R0, X1, W1_2 + 5 * 1296, ssA, R2, nullptr);
    cheb_step_kernel<36, 2, true, true, false><<<STEP_BLKS, 252, 0, stream>>>(
        rp, csrw, R2, R1, X1, W1_2 + 4 * 1296, ssA, R0, nullptr);
    cheb_step_kernel<36, 2, true, true, false><<<STEP_BLKS, 252, 0, stream>>>(
        rp, csrw, R0, R2, X1, W1_2 + 3 * 1296, ssA, R1, nullptr);
    cheb_step_kernel<36, 2, true, true, false><<<STEP_BLKS, 252, 0, stream>>>(
        rp, csrw, R1, R0, X1, W1_2 + 2 * 1296, ssA, R2, nullptr);
    cheb_step_kernel<36, 2, true, true, false><<<STEP_BLKS, 252, 0, stream>>>(
        rp, csrw, R2, R1, X1, W1_2 + 1 * 1296, ssA, R0, nullptr);
    cheb_step_kernel<36, 1, true, true, true><<<STEP_BLKS, 252, 0, stream>>>(
        rp, csrw, R0, R2, X1, W1_2 + 0 * 1296, ssA, X2, partials);
    finalize_kernel<<<1, 1008, 0, stream>>>(partials, STEP_BLKS, g1_2, be1_2, ssB);

    // ---- GIN ----
    gin_fused_kernel<<<GIN_BLKS, 256, 0, stream>>>(rp, csrw, x, gin_w1, gin_b1,
                                                   gin_w2, gin_b2, X3, partials);
    finalize_kernel<<<1, 1008, 0, stream>>>(partials, GIN_BLKS, g2, be2, ssC);

    // ---- final concat GEMM ----
    fused3_kernel<<<PROJ_BLKS, 256, 0, stream>>>(X1, ssA, X2, ssB, X3, ssC, W4, b4, out);
}

// Round 4
// 1359.301 us; speedup vs baseline: 1.2820x; 1.2820x over previous
//
#include <hip/hip_runtime.h>

constexpr int N_NODES = 100000;
constexpr int N_EDGES = 1600000;
constexpr int CHUNK_E = N_EDGES / 8;   // 200000

// ---------------- bf16 helpers (RNE) ----------------

__device__ __forceinline__ unsigned bf16pack(float a, float b) {
    unsigned ua = __float_as_uint(a), ub = __float_as_uint(b);
    ua += 0x7fffu + ((ua >> 16) & 1u);
    ub += 0x7fffu + ((ub >> 16) & 1u);
    return (ua >> 16) | (ub & 0xffff0000u);
}
__device__ __forceinline__ float bflo(unsigned p) { return __uint_as_float(p << 16); }
__device__ __forceinline__ float bfhi(unsigned p) { return __uint_as_float(p & 0xffff0000u); }

// ---------------- graph preprocessing ----------------

__global__ void hist8_kernel(const int* __restrict__ ei, int* __restrict__ deg8,
                             int* __restrict__ cnt8) {
    int c = blockIdx.x & 7;
    int lb = blockIdx.x >> 3;
    int* dg = deg8 + c * N_NODES;
    int* ct = cnt8 + c * N_NODES;
    int e_end = (c + 1) * CHUNK_E;
    for (int e = c * CHUNK_E + lb * 256 + threadIdx.x; e < e_end; e += 256 * 256) {
        int s = ei[e];
        int d = ei[N_EDGES + e];
        atomicAdd(&dg[s], 1);
        atomicAdd(&ct[d], 1);
    }
}

__global__ void scan1_kernel(const int* __restrict__ cnt8, const int* __restrict__ deg8,
                             int* __restrict__ rp, int* __restrict__ bsum,
                             float* __restrict__ dis) {
    __shared__ int sm[256];
    int i = blockIdx.x * 256 + threadIdx.x;
    int v = 0;
    if (i < N_NODES) {
        int dv = 0;
#pragma unroll
        for (int c = 0; c < 8; ++c) {
            v += cnt8[c * N_NODES + i];
            dv += deg8[c * N_NODES + i];
        }
        dis[i] = dv > 0 ? rsqrtf((float)dv) : 0.f;
    }
    sm[threadIdx.x] = v;
    __syncthreads();
    for (int off = 1; off < 256; off <<= 1) {
        int t = (threadIdx.x >= off) ? sm[threadIdx.x - off] : 0;
        __syncthreads();
        sm[threadIdx.x] += t;
        __syncthreads();
    }
    if (i < N_NODES) rp[i] = sm[threadIdx.x] - v;
    if (threadIdx.x == 255) bsum[blockIdx.x] = sm[255];
}

__global__ void scan2_kernel(int* __restrict__ bsum, int nb) {
    __shared__ int sm[512];
    int t = threadIdx.x;
    int v = (t < nb) ? bsum[t] : 0;
    sm[t] = v;
    __syncthreads();
    for (int off = 1; off < 512; off <<= 1) {
        int u = (t >= off) ? sm[t - off] : 0;
        __syncthreads();
        sm[t] += u;
        __syncthreads();
    }
    if (t < nb) bsum[t] = sm[t] - v;
}

__global__ void scan3_kernel(int* __restrict__ rp, const int* __restrict__ bsum,
                             const int* __restrict__ cnt8, int* __restrict__ rp8) {
    int i = blockIdx.x * 256 + threadIdx.x;
    if (i < N_NODES) {
        int base = rp[i] + bsum[blockIdx.x];
        rp[i] = base;
        int run = base;
#pragma unroll
        for (int c = 0; c < 8; ++c) {
            rp8[c * N_NODES + i] = run;
            run += cnt8[c * N_NODES + i];
        }
    }
    if (i == 0) rp[N_NODES] = N_EDGES;
}

__global__ void fill8_kernel(const int* __restrict__ ei, const int* __restrict__ rp8,
                             int* __restrict__ cur8, const float* __restrict__ dis,
                             int2* __restrict__ csrw) {
    int c = blockIdx.x & 7;
    int lb = blockIdx.x >> 3;
    const int* r8 = rp8 + c * N_NODES;
    int* cu = cur8 + c * N_NODES;
    int e_end = (c + 1) * CHUNK_E;
    for (int e = c * CHUNK_E + lb * 256 + threadIdx.x; e < e_end; e += 256 * 256) {
        int s = ei[e];
        int d = ei[N_EDGES + e];
        int pos = r8[d] + atomicAdd(&cu[d], 1);
        csrw[pos] = make_int2(s, __float_as_int(-dis[s] * dis[d]));
    }
}

// pack x [N,64] f32 -> bf16 (row = 128B = 1 cache line)
__global__ void pack_x_kernel(const float* __restrict__ x, uint2* __restrict__ xbf) {
    int i = blockIdx.x * blockDim.x + threadIdx.x;     // over N*16
    if (i >= N_NODES * 16) return;
    float4 v = ((const float4*)x)[i];
    xbf[i] = make_uint2(bf16pack(v.x, v.y), bf16pack(v.z, v.w));
}

// ---------------- fused Clenshaw step ----------------
// OUT[row] = SCALE * sum_j w_j*INb[src_j] + A'[row]@W - (HAS_B2 ? B2b[row] : 0)
// INb/B2b are bf16, row stride 16 uint2 (128B). SCALE==0 -> pure projection.
// A' = BN_A ? relu(ss*A+sh) : A.  OUT_BF16: write packed bf16, else f32.

template <int FI, int SCALE, bool HAS_B2, bool BN_A, bool FUSE_STATS, bool OUT_BF16>
__global__ __launch_bounds__(256) void cheb_step_kernel(
    const int* __restrict__ rp, const int2* __restrict__ csrw,
    const uint2* __restrict__ INb, const uint2* __restrict__ B2b,
    const float* __restrict__ A, const float* __restrict__ W,
    const float* __restrict__ ss, void* __restrict__ OUT,
    float* __restrict__ partials) {
    __shared__ float Wl[FI * 36];
    __shared__ float Atile[28][FI + 1];
    __shared__ float ls[72];
    int tid = threadIdx.x;                       // 252 threads = 28 rows x 9 lanes
    for (int i = tid; i < FI * 36; i += 252) Wl[i] = W[i];
    int r0 = blockIdx.x * 28;
    for (int i = tid; i < 28 * FI; i += 252) {
        int r = i / FI, f = i % FI;
        int row = r0 + r;
        float v = (row < N_NODES) ? A[row * FI + f] : 0.f;
        if (BN_A) v = fmaxf(fmaf(ss[f], v, ss[36 + f]), 0.f);
        Atile[r][f] = v;
    }
    if (FUSE_STATS && tid < 72) ls[tid] = 0.f;
    __syncthreads();
    int r = tid / 9, c = tid % 9;
    int row = r0 + r;
    bool valid = row < N_NODES;
    float ax = 0, ay = 0, az = 0, aw = 0;
    float bx = 0, by = 0, bz = 0, bw = 0;
    if (SCALE != 0 && valid) {
        int beg = rp[row], end = rp[row + 1];
        int j = beg;
        for (; j + 3 < end; j += 4) {            // 4 gathers in flight, 2 acc chains
            int2 e0 = csrw[j], e1 = csrw[j + 1], e2 = csrw[j + 2], e3 = csrw[j + 3];
            uint2 u0 = INb[e0.x * 16 + c];
            uint2 u1 = INb[e1.x * 16 + c];
            uint2 u2 = INb[e2.x * 16 + c];
            uint2 u3 = INb[e3.x * 16 + c];
            float w0 = __int_as_float(e0.y), w1 = __int_as_float(e1.y);
            float w2 = __int_as_float(e2.y), w3 = __int_as_float(e3.y);
            ax = fmaf(w0, bflo(u0.x), ax); ay = fmaf(w0, bfhi(u0.x), ay);
            az = fmaf(w0, bflo(u0.y), az); aw = fmaf(w0, bfhi(u0.y), aw);
            bx = fmaf(w1, bflo(u1.x), bx); by = fmaf(w1, bfhi(u1.x), by);
            bz = fmaf(w1, bflo(u1.y), bz); bw = fmaf(w1, bfhi(u1.y), bw);
            ax = fmaf(w2, bflo(u2.x), ax); ay = fmaf(w2, bfhi(u2.x), ay);
            az = fmaf(w2, bflo(u2.y), az); aw = fmaf(w2, bfhi(u2.y), aw);
            bx = fmaf(w3, bflo(u3.x), bx); by = fmaf(w3, bfhi(u3.x), by);
            bz = fmaf(w3, bflo(u3.y), bz); bw = fmaf(w3, bfhi(u3.y), bw);
        }
        for (; j < end; ++j) {
            int2 e = csrw[j];
            uint2 u = INb[e.x * 16 + c];
            float w = __int_as_float(e.y);
            ax = fmaf(w, bflo(u.x), ax); ay = fmaf(w, bfhi(u.x), ay);
            az = fmaf(w, bflo(u.y), az); aw = fmaf(w, bfhi(u.y), aw);
        }
        ax += bx; ay += by; az += bz; aw += bw;
    }
    float px = 0, py = 0, pz = 0, pw = 0;
    const float4* Wl4 = (const float4*)Wl;
#pragma unroll 4
    for (int f = 0; f < FI; ++f) {
        float a = Atile[r][f];
        float4 wv = Wl4[f * 9 + c];
        px = fmaf(a, wv.x, px); py = fmaf(a, wv.y, py);
        pz = fmaf(a, wv.z, pz); pw = fmaf(a, wv.w, pw);
    }
    const float S = (float)SCALE;
    float4 o;
    o.x = fmaf(S, ax, px); o.y = fmaf(S, ay, py);
    o.z = fmaf(S, az, pz); o.w = fmaf(S, aw, pw);
    if (valid) {
        if (HAS_B2) {
            uint2 u = B2b[row * 16 + c];
            o.x -= bflo(u.x); o.y -= bfhi(u.x);
            o.z -= bflo(u.y); o.w -= bfhi(u.y);
        }
        if (OUT_BF16) {
            ((uint2*)OUT)[row * 16 + c] =
                make_uint2(bf16pack(o.x, o.y), bf16pack(o.z, o.w));
        } else {
            ((float4*)OUT)[row * 9 + c] = o;
        }
        if (FUSE_STATS) {
            atomicAdd(&ls[c * 4 + 0], o.x); atomicAdd(&ls[36 + c * 4 + 0], o.x * o.x);
            atomicAdd(&ls[c * 4 + 1], o.y); atomicAdd(&ls[36 + c * 4 + 1], o.y * o.y);
            atomicAdd(&ls[c * 4 + 2], o.z); atomicAdd(&ls[36 + c * 4 + 2], o.z * o.z);
            atomicAdd(&ls[c * 4 + 3], o.w); atomicAdd(&ls[36 + c * 4 + 3], o.w * o.w);
        }
    }
    if (FUSE_STATS) {
        __syncthreads();
        if (tid < 72) partials[blockIdx.x * 72 + tid] = ls[tid];
    }
}

// ---------------- GIN mega-kernel ----------------
// OUT[row] = relu( relu( (x[row]+sum xbf[src]) @ w1 + b1 ) @ w2 + b2 ), + stats

__global__ __launch_bounds__(256) void gin_fused_kernel(
    const int* __restrict__ rp, const int2* __restrict__ csrw,
    const float* __restrict__ X, const uint2* __restrict__ Xb,
    const float* __restrict__ w1, const float* __restrict__ b1,
    const float* __restrict__ w2, const float* __restrict__ b2,
    float* __restrict__ OUT, float* __restrict__ partials) {
    __shared__ float W1l[64 * 36];
    __shared__ float W2l[36 * 36];
    __shared__ float B1l[36], B2l[36];
    __shared__ float Ht[16][68];
    __shared__ float M1t[16][40];
    __shared__ float ls[72];
    int tid = threadIdx.x;                       // 256 = 16 rows x 16 lanes
    for (int i = tid; i < 64 * 36; i += 256) W1l[i] = w1[i];
    for (int i = tid; i < 36 * 36; i += 256) W2l[i] = w2[i];
    if (tid < 36) { B1l[tid] = b1[tid]; B2l[tid] = b2[tid]; }
    if (tid < 72) ls[tid] = 0.f;
    int r = tid >> 4, l = tid & 15;
    int row = blockIdx.x * 16 + r;
    bool valid = row < N_NODES;
    float hx = 0, hy = 0, hz = 0, hw = 0;
    float gx = 0, gy = 0, gz = 0, gw = 0;
    if (valid) {
        float4 self = ((const float4*)X)[row * 16 + l];
        hx = self.x; hy = self.y; hz = self.z; hw = self.w;
        int beg = rp[row], end = rp[row + 1];
        int j = beg;
        for (; j + 3 < end; j += 4) {
            int s0 = csrw[j].x, s1 = csrw[j + 1].x, s2 = csrw[j + 2].x, s3 = csrw[j + 3].x;
            uint2 u0 = Xb[s0 * 16 + l];
            uint2 u1 = Xb[s1 * 16 + l];
            uint2 u2 = Xb[s2 * 16 + l];
            uint2 u3 = Xb[s3 * 16 + l];
            hx += bflo(u0.x) + bflo(u1.x); hy += bfhi(u0.x) + bfhi(u1.x);
            hz += bflo(u0.y) + bflo(u1.y); hw += bfhi(u0.y) + bfhi(u1.y);
            gx += bflo(u2.x) + bflo(u3.x); gy += bfhi(u2.x) + bfhi(u3.x);
            gz += bflo(u2.y) + bflo(u3.y); gw += bfhi(u2.y) + bfhi(u3.y);
        }
        for (; j < end; ++j) {
            uint2 u = Xb[csrw[j].x * 16 + l];
            hx += bflo(u.x); hy += bfhi(u.x);
            hz += bflo(u.y); hw += bfhi(u.y);
        }
        hx += gx; hy += gy; hz += gz; hw += gw;
    }
    Ht[r][l * 4 + 0] = hx; Ht[r][l * 4 + 1] = hy;
    Ht[r][l * 4 + 2] = hz; Ht[r][l * 4 + 3] = hw;
    __syncthreads();
    float m1a = B1l[l], m1b = B1l[l + 16], m1c = (l < 4) ? B1l[l + 32] : 0.f;
#pragma unroll 4
    for (int f = 0; f < 64; ++f) {
        float a = Ht[r][f];
        m1a = fmaf(a, W1l[f * 36 + l], m1a);
        m1b = fmaf(a, W1l[f * 36 + l + 16], m1b);
        if (l < 4) m1c = fmaf(a, W1l[f * 36 + l + 32], m1c);
    }
    m1a = fmaxf(m1a, 0.f); m1b = fmaxf(m1b, 0.f); m1c = fmaxf(m1c, 0.f);
    M1t[r][l] = m1a; M1t[r][l + 16] = m1b;
    if (l < 4) M1t[r][l + 32] = m1c;
    __syncthreads();
    float m2a = B2l[l], m2b = B2l[l + 16], m2c = (l < 4) ? B2l[l + 32] : 0.f;
#pragma unroll 4
    for (int f = 0; f < 36; ++f) {
        float a = M1t[r][f];
        m2a = fmaf(a, W2l[f * 36 + l], m2a);
        m2b = fmaf(a, W2l[f * 36 + l + 16], m2b);
        if (l < 4) m2c = fmaf(a, W2l[f * 36 + l + 32], m2c);
    }
    m2a = fmaxf(m2a, 0.f); m2b = fmaxf(m2b, 0.f); m2c = fmaxf(m2c, 0.f);
    if (valid) {
        OUT[row * 36 + l] = m2a;
        OUT[row * 36 + l + 16] = m2b;
        if (l < 4) OUT[row * 36 + l + 32] = m2c;
        atomicAdd(&ls[l], m2a); atomicAdd(&ls[36 + l], m2a * m2a);
        atomicAdd(&ls[l + 16], m2b); atomicAdd(&ls[36 + l + 16], m2b * m2b);
        if (l < 4) { atomicAdd(&ls[l + 32], m2c); atomicAdd(&ls[36 + l + 32], m2c * m2c); }
    }
    __syncthreads();
    if (tid < 72) partials[blockIdx.x * 72 + tid] = ls[tid];
}

// ---------------- finalize: reduce partials -> BN scale/shift ----------------

__global__ __launch_bounds__(1024) void finalize_kernel(
    const float* __restrict__ partials, int nb, const float* __restrict__ g,
    const float* __restrict__ be, float* __restrict__ ss) {
    __shared__ float red[14][72];
    __shared__ float tot[72];
    int tid = threadIdx.x;                       // 1008 = 14 x 72
    int grp = tid / 72, c = tid % 72;
    float s = 0.f;
    for (int i = grp; i < nb; i += 14) s += partials[i * 72 + c];
    red[grp][c] = s;
    __syncthreads();
    if (grp == 0) {
        float t = 0.f;
#pragma unroll
        for (int k = 0; k < 14; ++k) t += red[k][c];
        tot[c] = t;
    }
    __syncthreads();
    if (tid < 36) {
        float m = tot[tid] / (float)N_NODES;
        float v = tot[36 + tid] / (float)N_NODES - m * m;
        float sc = g[tid] * rsqrtf(v + 1e-5f);
        ss[tid] = sc;
        ss[36 + tid] = be[tid] - m * sc;
    }
}

// ---------------- final concat GEMM with BN folds ----------------

__global__ __launch_bounds__(256) void fused3_kernel(
    const float* __restrict__ X1, const float* __restrict__ ssA,
    const float* __restrict__ X2, const float* __restrict__ ssB,
    const float* __restrict__ X3, const float* __restrict__ ssC,
    const float* __restrict__ W, const float* __restrict__ b,
    float* __restrict__ out) {
    __shared__ float Wl[108 * 32];
    __shared__ float Al[64][109];
    int tid = threadIdx.x;
    for (int i = tid; i < 108 * 32; i += 256) Wl[i] = W[i];
    int r0 = blockIdx.x * 64;
    for (int i = tid; i < 64 * 108; i += 256) {
        int r = i / 108, f = i % 108;
        int row = r0 + r;
        float v = 0.f;
        if (row < N_NODES) {
            if (f < 36) {
                v = fmaxf(fmaf(ssA[f], X1[row * 36 + f], ssA[36 + f]), 0.f);
            } else if (f < 72) {
                int ff = f - 36;
                v = fmaxf(fmaf(ssB[ff], X2[row * 36 + ff], ssB[36 + ff]), 0.f);
            } else {
                int ff = f - 72;
                v = fmaf(ssC[ff], X3[row * 36 + ff], ssC[36 + ff]);
            }
        }
        Al[r][f] = v;
    }
    __syncthreads();
    int r = tid >> 2, q = tid & 3;
    int row = r0 + r;
    if (row >= N_NODES) return;
    float acc[8];
#pragma unroll
    for (int j = 0; j < 8; ++j) acc[j] = b[q * 8 + j];
    for (int f = 0; f < 108; ++f) {
        float a = Al[r][f];
#pragma unroll
        for (int j = 0; j < 8; ++j)
            acc[j] = fmaf(a, Wl[f * 32 + q * 8 + j], acc[j]);
    }
#pragma unroll
    for (int j = 0; j < 8; ++j) out[row * 32 + q * 8 + j] = acc[j];
}

// ---------------- launch ----------------

extern "C" void kernel_launch(void* const* d_in, const int* in_sizes, int n_in,
                              void* d_out, int out_size, void* d_ws, size_t ws_size,
                              hipStream_t stream) {
    const float* x      = (const float*)d_in[0];
    const int*   ei     = (const int*)d_in[1];
    const float* W1_1   = (const float*)d_in[2];
    // b1_1 / b1_2 cancel exactly under training-mode BN -> dropped.
    const float* g1_1   = (const float*)d_in[4];
    const float* be1_1  = (const float*)d_in[5];
    const float* W1_2   = (const float*)d_in[6];
    const float* g1_2   = (const float*)d_in[8];
    const float* be1_2  = (const float*)d_in[9];
    const float* gin_w1 = (const float*)d_in[10];
    const float* gin_b1 = (const float*)d_in[11];
    const float* gin_w2 = (const float*)d_in[12];
    const float* gin_b2 = (const float*)d_in[13];
    const float* g2     = (const float*)d_in[14];
    const float* be2    = (const float*)d_in[15];
    const float* W4     = (const float*)d_in[16];
    const float* b4     = (const float*)d_in[17];
    float* out = (float*)d_out;

    char* ws = (char*)d_ws;
    size_t off = 0;
    auto alloc = [&](size_t bytes) -> char* {
        char* p = ws + off;
        off = (off + bytes + 255) & ~(size_t)255;
        return p;
    };
    int*   cnt8  = (int*)alloc((size_t)8 * N_NODES * 4);
    int*   deg8  = (int*)alloc((size_t)8 * N_NODES * 4);   // reused as cur8
    size_t zend = off;
    int*   rp    = (int*)alloc((size_t)(N_NODES + 1) * 4);
    int*   rp8   = (int*)alloc((size_t)8 * N_NODES * 4);
    int*   bsum  = (int*)alloc(512 * 4);
    float* dis   = (float*)alloc((size_t)N_NODES * 4);
    int2*  csrw  = (int2*)alloc((size_t)N_EDGES * 8);
    float* ssA   = (float*)alloc(72 * 4);
    float* ssB   = (float*)alloc(72 * 4);
    float* ssC   = (float*)alloc(72 * 4);
    float* partials = (float*)alloc((size_t)6250 * 72 * 4);
    constexpr size_t NB36 = (size_t)N_NODES * 36 * 4;      // f32 [N,36]
    constexpr size_t NBBF = (size_t)N_NODES * 128;         // bf16 [N,64] rows (128B)
    uint2* xbf = (uint2*)alloc(NBBF);
    uint2* R0  = (uint2*)alloc(NBBF);
    uint2* R1  = (uint2*)alloc(NBBF);
    uint2* R2  = (uint2*)alloc(NBBF);
    float* X1  = (float*)alloc(NB36);
    float* X2  = (float*)alloc(NB36);
    float* X3  = (float*)alloc(NB36);
    if (off > ws_size) return;

    hipMemsetAsync(d_ws, 0, zend, stream);

    const int SCAN_BLKS = (N_NODES + 255) / 256;      // 391
    hist8_kernel<<<2048, 256, 0, stream>>>(ei, deg8, cnt8);
    scan1_kernel<<<SCAN_BLKS, 256, 0, stream>>>(cnt8, deg8, rp, bsum, dis);
    scan2_kernel<<<1, 512, 0, stream>>>(bsum, SCAN_BLKS);
    scan3_kernel<<<SCAN_BLKS, 256, 0, stream>>>(rp, bsum, cnt8, rp8);
    hipMemsetAsync(deg8, 0, (size_t)8 * N_NODES * 4, stream);
    fill8_kernel<<<2048, 256, 0, stream>>>(ei, rp8, deg8, dis, csrw);
    pack_x_kernel<<<(N_NODES * 16 + 255) / 256, 256, 0, stream>>>(x, xbf);

    const int STEP_BLKS = (N_NODES + 27) / 28;        // 3572
    const int GIN_BLKS  = (N_NODES + 15) / 16;        // 6250
    const int F3_BLKS   = (N_NODES + 63) / 64;        // 1563

    // ---- conv1_1 (Clenshaw, FI=64, A=x) ----
    // b7 -> R0; b6 -> R1; b5 -> R2; b4 -> R0; b3 -> R1; b2 -> R2; b1 -> R0;
    // X1 = y0 + L*b1 - b2
    cheb_step_kernel<64, 0, false, false, false, true><<<STEP_BLKS, 252, 0, stream>>>(
        rp, csrw, nullptr, nullptr, x, W1_1 + 7 * 2304, nullptr, R0, nullptr);
    cheb_step_kernel<64, 2, false, false, false, true><<<STEP_BLKS, 252, 0, stream>>>(
        rp, csrw, R0, nullptr, x, W1_1 + 6 * 2304, nullptr, R1, nullptr);
    cheb_step_kernel<64, 2, true, false, false, true><<<STEP_BLKS, 252, 0, stream>>>(
        rp, csrw, R1, R0, x, W1_1 + 5 * 2304, nullptr, R2, nullptr);
    cheb_step_kernel<64, 2, true, false, false, true><<<STEP_BLKS, 252, 0, stream>>>(
        rp, csrw, R2, R1, x, W1_1 + 4 * 2304, nullptr, R0, nullptr);
    cheb_step_kernel<64, 2, true, false, false, true><<<STEP_BLKS, 252, 0, stream>>>(
        rp, csrw, R0, R2, x, W1_1 + 3 * 2304, nullptr, R1, nullptr);
    cheb_step_kernel<64, 2, true, false, false, true><<<STEP_BLKS, 252, 0, stream>>>(
        rp, csrw, R1, R0, x, W1_1 + 2 * 2304, nullptr, R2, nullptr);
    cheb_step_kernel<64, 2, true, false, false, true><<<STEP_BLKS, 252, 0, stream>>>(
        rp, csrw, R2, R1, x, W1_1 + 1 * 2304, nullptr, R0, nullptr);
    cheb_step_kernel<64, 1, true, false, true, false><<<STEP_BLKS, 252, 0, stream>>>(
        rp, csrw, R0, R2, x, W1_1 + 0 * 2304, nullptr, X1, partials);
    finalize_kernel<<<1, 1008, 0, stream>>>(partials, STEP_BLKS, g1_1, be1_1, ssA);

    // ---- conv1_2 (Clenshaw, FI=36, A=X1 with BN ssA) ----
    cheb_step_kernel<36, 0, false, true, false, true><<<STEP_BLKS, 252, 0, stream>>>(
        rp, csrw, nullptr, nullptr, X1, W1_2 + 7 * 1296, ssA, R0, nullptr);
    cheb_step_kernel<36, 2, false, true, false, true><<<STEP_BLKS, 252, 0, stream>>>(
        rp, csrw, R0, nullptr, X1, W1_2 + 6 * 1296, ssA, R1, nullptr);
    cheb_step_kernel<36, 2, true, true, false, true><<<STEP_BLKS, 252, 0, stream>>>(
        rp, csrw, R1, R0, X1, W1_2 + 5 * 1296, ssA, R2, nullptr);
    cheb_step_kernel<36, 2, true, true, false, true><<<STEP_BLKS, 252, 0, stream>>>(
        rp, csrw, R2, R1, X1, W1_2 + 4 * 1296, ssA, R0, nullptr);
    cheb_step_kernel<36, 2, true, true, false, true><<<STEP_BLKS, 252, 0, stream>>>(
        rp, csrw, R0, R2, X1, W1_2 + 3 * 1296, ssA, R1, nullptr);
    cheb_step_kernel<36, 2, true, true, false, true><<<STEP_BLKS, 252, 0, stream>>>(
        rp, csrw, R1, R0, X1, W1_2 + 2 * 1296, ssA, R2, nullptr);
    cheb_step_kernel<36, 2, true, true, false, true><<<STEP_BLKS, 252, 0, stream>>>(
        rp, csrw, R2, R1, X1, W1_2 + 1 * 1296, ssA, R0, nullptr);
    cheb_step_kernel<36, 1, true, true, true, false><<<STEP_BLKS, 252, 0, stream>>>(
        rp, csrw, R0, R2, X1, W1_2 + 0 * 1296, ssA, X2, partials);
    finalize_kernel<<<1, 1008, 0, stream>>>(partials, STEP_BLKS, g1_2, be1_2, ssB);

    // ---- GIN ----
    gin_fused_kernel<<<GIN_BLKS, 256, 0, stream>>>(rp, csrw, x, xbf, gin_w1, gin_b1,
                                                   gin_w2, gin_b2, X3, partials);
    finalize_kernel<<<1, 1008, 0, stream>>>(partials, GIN_BLKS, g2, be2, ssC);

    // ---- final concat GEMM ----
    fused3_kernel<<<F3_BLKS, 256, 0, stream>>>(X1, ssA, X2, ssB, X3, ssC, W4, b4, out);
}

// Round 5
// 1132.307 us; speedup vs baseline: 1.5389x; 1.2005x over previous
//
#include <hip/hip_runtime.h>

constexpr int N_NODES = 100000;
constexpr int N_EDGES = 1600000;
constexpr int CHUNK_E = N_EDGES / 8;   // 200000

// ---------------- bf16 helpers (RNE) ----------------

__device__ __forceinline__ unsigned bf16pack(float a, float b) {
    unsigned ua = __float_as_uint(a), ub = __float_as_uint(b);
    ua += 0x7fffu + ((ua >> 16) & 1u);
    ub += 0x7fffu + ((ub >> 16) & 1u);
    return (ua >> 16) | (ub & 0xffff0000u);
}
__device__ __forceinline__ float bflo(unsigned p) { return __uint_as_float(p << 16); }
__device__ __forceinline__ float bfhi(unsigned p) { return __uint_as_float(p & 0xffff0000u); }

// ---------------- graph preprocessing ----------------

__global__ void hist8_kernel(const int* __restrict__ ei, int* __restrict__ deg8,
                             int* __restrict__ cnt8) {
    int c = blockIdx.x & 7;
    int lb = blockIdx.x >> 3;
    int* dg = deg8 + c * N_NODES;
    int* ct = cnt8 + c * N_NODES;
    int e_end = (c + 1) * CHUNK_E;
    for (int e = c * CHUNK_E + lb * 256 + threadIdx.x; e < e_end; e += 256 * 256) {
        int s = ei[e];
        int d = ei[N_EDGES + e];
        atomicAdd(&dg[s], 1);
        atomicAdd(&ct[d], 1);
    }
}

__global__ void scan1_kernel(const int* __restrict__ cnt8, const int* __restrict__ deg8,
                             int* __restrict__ rp, int* __restrict__ bsum,
                             float* __restrict__ dis) {
    __shared__ int sm[256];
    int i = blockIdx.x * 256 + threadIdx.x;
    int v = 0;
    if (i < N_NODES) {
        int dv = 0;
#pragma unroll
        for (int c = 0; c < 8; ++c) {
            v += cnt8[c * N_NODES + i];
            dv += deg8[c * N_NODES + i];
        }
        dis[i] = dv > 0 ? rsqrtf((float)dv) : 0.f;
    }
    sm[threadIdx.x] = v;
    __syncthreads();
    for (int off = 1; off < 256; off <<= 1) {
        int t = (threadIdx.x >= off) ? sm[threadIdx.x - off] : 0;
        __syncthreads();
        sm[threadIdx.x] += t;
        __syncthreads();
    }
    if (i < N_NODES) rp[i] = sm[threadIdx.x] - v;
    if (threadIdx.x == 255) bsum[blockIdx.x] = sm[255];
}

__global__ void scan2_kernel(int* __restrict__ bsum, int nb) {
    __shared__ int sm[512];
    int t = threadIdx.x;
    int v = (t < nb) ? bsum[t] : 0;
    sm[t] = v;
    __syncthreads();
    for (int off = 1; off < 512; off <<= 1) {
        int u = (t >= off) ? sm[t - off] : 0;
        __syncthreads();
        sm[t] += u;
        __syncthreads();
    }
    if (t < nb) bsum[t] = sm[t] - v;
}

__global__ void scan3_kernel(int* __restrict__ rp, const int* __restrict__ bsum,
                             const int* __restrict__ cnt8, int* __restrict__ rp8) {
    int i = blockIdx.x * 256 + threadIdx.x;
    if (i < N_NODES) {
        int base = rp[i] + bsum[blockIdx.x];
        rp[i] = base;
        int run = base;
#pragma unroll
        for (int c = 0; c < 8; ++c) {
            rp8[c * N_NODES + i] = run;
            run += cnt8[c * N_NODES + i];
        }
    }
    if (i == 0) rp[N_NODES] = N_EDGES;
}

__global__ void fill8_kernel(const int* __restrict__ ei, const int* __restrict__ rp8,
                             int* __restrict__ cur8, const float* __restrict__ dis,
                             int2* __restrict__ csrw) {
    int c = blockIdx.x & 7;
    int lb = blockIdx.x >> 3;
    const int* r8 = rp8 + c * N_NODES;
    int* cu = cur8 + c * N_NODES;
    int e_end = (c + 1) * CHUNK_E;
    for (int e = c * CHUNK_E + lb * 256 + threadIdx.x; e < e_end; e += 256 * 256) {
        int s = ei[e];
        int d = ei[N_EDGES + e];
        int pos = r8[d] + atomicAdd(&cu[d], 1);
        csrw[pos] = make_int2(s, __float_as_int(-dis[s] * dis[d]));
    }
}

// pack x [N,64] f32 -> bf16 (row = 128B = 1 cache line)
__global__ void pack_x_kernel(const float* __restrict__ x, uint2* __restrict__ xbf) {
    int i = blockIdx.x * blockDim.x + threadIdx.x;     // over N*16
    if (i >= N_NODES * 16) return;
    float4 v = ((const float4*)x)[i];
    xbf[i] = make_uint2(bf16pack(v.x, v.y), bf16pack(v.z, v.w));
}

// ---------------- fused Clenshaw step ----------------
// OUT[row] = SCALE * sum_j w_j*INb[src_j] + A'[row]@W - (HAS_B2 ? B2b[row] : 0)
// INb/B2b are bf16, row stride 16 uint2 (128B). SCALE==0 -> pure projection.
// A' = BN_A ? relu(ss*A+sh) : A.  OUT_BF16: write packed bf16, else f32.

template <int FI, int SCALE, bool HAS_B2, bool BN_A, bool FUSE_STATS, bool OUT_BF16>
__global__ __launch_bounds__(256) void cheb_step_kernel(
    const int* __restrict__ rp, const int2* __restrict__ csrw,
    const uint2* __restrict__ INb, const uint2* __restrict__ B2b,
    const float* __restrict__ A, const float* __restrict__ W,
    const float* __restrict__ ss, void* __restrict__ OUT,
    float* __restrict__ partials) {
    __shared__ float Wl[FI * 36];
    __shared__ float Atile[28][FI + 1];
    __shared__ float ls[72];
    int tid = threadIdx.x;                       // 252 threads = 28 rows x 9 lanes
    for (int i = tid; i < FI * 36; i += 252) Wl[i] = W[i];
    int r0 = blockIdx.x * 28;
    for (int i = tid; i < 28 * FI; i += 252) {
        int r = i / FI, f = i % FI;
        int row = r0 + r;
        float v = (row < N_NODES) ? A[row * FI + f] : 0.f;
        if (BN_A) v = fmaxf(fmaf(ss[f], v, ss[36 + f]), 0.f);
        Atile[r][f] = v;
    }
    if (FUSE_STATS && tid < 72) ls[tid] = 0.f;
    __syncthreads();
    int r = tid / 9, c = tid % 9;
    int row = r0 + r;
    bool valid = row < N_NODES;
    float ax = 0, ay = 0, az = 0, aw = 0;
    float bx = 0, by = 0, bz = 0, bw = 0;
    if (SCALE != 0 && valid) {
        int beg = rp[row], end = rp[row + 1];
        int j = beg;
        for (; j + 3 < end; j += 4) {            // 4 gathers in flight, 2 acc chains
            int2 e0 = csrw[j], e1 = csrw[j + 1], e2 = csrw[j + 2], e3 = csrw[j + 3];
            uint2 u0 = INb[e0.x * 16 + c];
            uint2 u1 = INb[e1.x * 16 + c];
            uint2 u2 = INb[e2.x * 16 + c];
            uint2 u3 = INb[e3.x * 16 + c];
            float w0 = __int_as_float(e0.y), w1 = __int_as_float(e1.y);
            float w2 = __int_as_float(e2.y), w3 = __int_as_float(e3.y);
            ax = fmaf(w0, bflo(u0.x), ax); ay = fmaf(w0, bfhi(u0.x), ay);
            az = fmaf(w0, bflo(u0.y), az); aw = fmaf(w0, bfhi(u0.y), aw);
            bx = fmaf(w1, bflo(u1.x), bx); by = fmaf(w1, bfhi(u1.x), by);
            bz = fmaf(w1, bflo(u1.y), bz); bw = fmaf(w1, bfhi(u1.y), bw);
            ax = fmaf(w2, bflo(u2.x), ax); ay = fmaf(w2, bfhi(u2.x), ay);
            az = fmaf(w2, bflo(u2.y), az); aw = fmaf(w2, bfhi(u2.y), aw);
            bx = fmaf(w3, bflo(u3.x), bx); by = fmaf(w3, bfhi(u3.x), by);
            bz = fmaf(w3, bflo(u3.y), bz); bw = fmaf(w3, bfhi(u3.y), bw);
        }
        for (; j < end; ++j) {
            int2 e = csrw[j];
            uint2 u = INb[e.x * 16 + c];
            float w = __int_as_float(e.y);
            ax = fmaf(w, bflo(u.x), ax); ay = fmaf(w, bfhi(u.x), ay);
            az = fmaf(w, bflo(u.y), az); aw = fmaf(w, bfhi(u.y), aw);
        }
        ax += bx; ay += by; az += bz; aw += bw;
    }
    float px = 0, py = 0, pz = 0, pw = 0;
    const float4* Wl4 = (const float4*)Wl;
#pragma unroll 4
    for (int f = 0; f < FI; ++f) {
        float a = Atile[r][f];
        float4 wv = Wl4[f * 9 + c];
        px = fmaf(a, wv.x, px); py = fmaf(a, wv.y, py);
        pz = fmaf(a, wv.z, pz); pw = fmaf(a, wv.w, pw);
    }
    const float S = (float)SCALE;
    float4 o;
    o.x = fmaf(S, ax, px); o.y = fmaf(S, ay, py);
    o.z = fmaf(S, az, pz); o.w = fmaf(S, aw, pw);
    if (valid) {
        if (HAS_B2) {
            uint2 u = B2b[row * 16 + c];
            o.x -= bflo(u.x); o.y -= bfhi(u.x);
            o.z -= bflo(u.y); o.w -= bfhi(u.y);
        }
        if (OUT_BF16) {
            ((uint2*)OUT)[row * 16 + c] =
                make_uint2(bf16pack(o.x, o.y), bf16pack(o.z, o.w));
        } else {
            ((float4*)OUT)[row * 9 + c] = o;
        }
        if (FUSE_STATS) {
            atomicAdd(&ls[c * 4 + 0], o.x); atomicAdd(&ls[36 + c * 4 + 0], o.x * o.x);
            atomicAdd(&ls[c * 4 + 1], o.y); atomicAdd(&ls[36 + c * 4 + 1], o.y * o.y);
            atomicAdd(&ls[c * 4 + 2], o.z); atomicAdd(&ls[36 + c * 4 + 2], o.z * o.z);
            atomicAdd(&ls[c * 4 + 3], o.w); atomicAdd(&ls[36 + c * 4 + 3], o.w * o.w);
        }
    }
    if (FUSE_STATS) {
        __syncthreads();
        if (tid < 72) partials[blockIdx.x * 72 + tid] = ls[tid];
    }
}

// ---------------- GIN mega-kernel ----------------
// OUT[row] = relu( relu( (x[row]+sum xbf[src]) @ w1 + b1 ) @ w2 + b2 ), + stats

__global__ __launch_bounds__(256) void gin_fused_kernel(
    const int* __restrict__ rp, const int2* __restrict__ csrw,
    const float* __restrict__ X, const uint2* __restrict__ Xb,
    const float* __restrict__ w1, const float* __restrict__ b1,
    const float* __restrict__ w2, const float* __restrict__ b2,
    float* __restrict__ OUT, float* __restrict__ partials) {
    __shared__ float W1l[64 * 36];
    __shared__ float W2l[36 * 36];
    __shared__ float B1l[36], B2l[36];
    __shared__ float Ht[16][68];
    __shared__ float M1t[16][40];
    __shared__ float ls[72];
    int tid = threadIdx.x;                       // 256 = 16 rows x 16 lanes
    for (int i = tid; i < 64 * 36; i += 256) W1l[i] = w1[i];
    for (int i = tid; i < 36 * 36; i += 256) W2l[i] = w2[i];
    if (tid < 36) { B1l[tid] = b1[tid]; B2l[tid] = b2[tid]; }
    if (tid < 72) ls[tid] = 0.f;
    int r = tid >> 4, l = tid & 15;
    int row = blockIdx.x * 16 + r;
    bool valid = row < N_NODES;
    float hx = 0, hy = 0, hz = 0, hw = 0;
    float gx = 0, gy = 0, gz = 0, gw = 0;
    if (valid) {
        float4 self = ((const float4*)X)[row * 16 + l];
        hx = self.x; hy = self.y; hz = self.z; hw = self.w;
        int beg = rp[row], end = rp[row + 1];
        int j = beg;
        for (; j + 3 < end; j += 4) {
            int s0 = csrw[j].x, s1 = csrw[j + 1].x, s2 = csrw[j + 2].x, s3 = csrw[j + 3].x;
            uint2 u0 = Xb[s0 * 16 + l];
            uint2 u1 = Xb[s1 * 16 + l];
            uint2 u2 = Xb[s2 * 16 + l];
            uint2 u3 = Xb[s3 * 16 + l];
            hx += bflo(u0.x) + bflo(u1.x); hy += bfhi(u0.x) + bfhi(u1.x);
            hz += bflo(u0.y) + bflo(u1.y); hw += bfhi(u0.y) + bfhi(u1.y);
            gx += bflo(u2.x) + bflo(u3.x); gy += bfhi(u2.x) + bfhi(u3.x);
            gz += bflo(u2.y) + bflo(u3.y); gw += bfhi(u2.y) + bfhi(u3.y);
        }
        for (; j < end; ++j) {
            uint2 u = Xb[csrw[j].x * 16 + l];
            hx += bflo(u.x); hy += bfhi(u.x);
            hz += bflo(u.y); hw += bfhi(u.y);
        }
        hx += gx; hy += gy; hz += gz; hw += gw;
    }
    Ht[r][l * 4 + 0] = hx; Ht[r][l * 4 + 1] = hy;
    Ht[r][l * 4 + 2] = hz; Ht[r][l * 4 + 3] = hw;
    __syncthreads();
    float m1a = B1l[l], m1b = B1l[l + 16], m1c = (l < 4) ? B1l[l + 32] : 0.f;
#pragma unroll 4
    for (int f = 0; f < 64; ++f) {
        float a = Ht[r][f];
        m1a = fmaf(a, W1l[f * 36 + l], m1a);
        m1b = fmaf(a, W1l[f * 36 + l + 16], m1b);
        if (l < 4) m1c = fmaf(a, W1l[f * 36 + l + 32], m1c);
    }
    m1a = fmaxf(m1a, 0.f); m1b = fmaxf(m1b, 0.f); m1c = fmaxf(m1c, 0.f);
    M1t[r][l] = m1a; M1t[r][l + 16] = m1b;
    if (l < 4) M1t[r][l + 32] = m1c;
    __syncthreads();
    float m2a = B2l[l], m2b = B2l[l + 16], m2c = (l < 4) ? B2l[l + 32] : 0.f;
#pragma unroll 4
    for (int f = 0; f < 36; ++f) {
        float a = M1t[r][f];
        m2a = fmaf(a, W2l[f * 36 + l], m2a);
        m2b = fmaf(a, W2l[f * 36 + l + 16], m2b);
        if (l < 4) m2c = fmaf(a, W2l[f * 36 + l + 32], m2c);
    }
    m2a = fmaxf(m2a, 0.f); m2b = fmaxf(m2b, 0.f); m2c = fmaxf(m2c, 0.f);
    if (valid) {
        OUT[row * 36 + l] = m2a;
        OUT[row * 36 + l + 16] = m2b;
        if (l < 4) OUT[row * 36 + l + 32] = m2c;
        atomicAdd(&ls[l], m2a); atomicAdd(&ls[36 + l], m2a * m2a);
        atomicAdd(&ls[l + 16], m2b); atomicAdd(&ls[36 + l + 16], m2b * m2b);
        if (l < 4) { atomicAdd(&ls[l + 32], m2c); atomicAdd(&ls[36 + l + 32], m2c * m2c); }
    }
    __syncthreads();
    if (tid < 72) partials[blockIdx.x * 72 + tid] = ls[tid];
}

// ---------------- finalize: reduce partials -> BN scale/shift ----------------
// grid = 36 blocks; block c reduces columns c (sum) and c+36 (sumsq).
// 256 threads grid-stride the nb rows -> latency hidden across 36 CUs.

__global__ __launch_bounds__(256) void finalize_kernel(
    const float* __restrict__ partials, int nb, const float* __restrict__ g,
    const float* __restrict__ be, float* __restrict__ ss) {
    __shared__ float rs[256], rq[256];
    int c = blockIdx.x;
    int t = threadIdx.x;
    float s = 0.f, q = 0.f;
    for (int i = t; i < nb; i += 256) {
        s += partials[i * 72 + c];
        q += partials[i * 72 + c + 36];
    }
    rs[t] = s; rq[t] = q;
    __syncthreads();
    for (int off = 128; off > 0; off >>= 1) {
        if (t < off) { rs[t] += rs[t + off]; rq[t] += rq[t + off]; }
        __syncthreads();
    }
    if (t == 0) {
        float m = rs[0] / (float)N_NODES;
        float v = rq[0] / (float)N_NODES - m * m;
        float sc = g[c] * rsqrtf(v + 1e-5f);
        ss[c] = sc;
        ss[36 + c] = be[c] - m * sc;
    }
}

// ---------------- final concat GEMM with BN folds ----------------

__global__ __launch_bounds__(256) void fused3_kernel(
    const float* __restrict__ X1, const float* __restrict__ ssA,
    const float* __restrict__ X2, const float* __restrict__ ssB,
    const float* __restrict__ X3, const float* __restrict__ ssC,
    const float* __restrict__ W, const float* __restrict__ b,
    float* __restrict__ out) {
    __shared__ float Wl[108 * 32];
    __shared__ float Al[64][109];
    int tid = threadIdx.x;
    for (int i = tid; i < 108 * 32; i += 256) Wl[i] = W[i];
    int r0 = blockIdx.x * 64;
    for (int i = tid; i < 64 * 108; i += 256) {
        int r = i / 108, f = i % 108;
        int row = r0 + r;
        float v = 0.f;
        if (row < N_NODES) {
            if (f < 36) {
                v = fmaxf(fmaf(ssA[f], X1[row * 36 + f], ssA[36 + f]), 0.f);
            } else if (f < 72) {
                int ff = f - 36;
                v = fmaxf(fmaf(ssB[ff], X2[row * 36 + ff], ssB[36 + ff]), 0.f);
            } else {
                int ff = f - 72;
                v = fmaf(ssC[ff], X3[row * 36 + ff], ssC[36 + ff]);
            }
        }
        Al[r][f] = v;
    }
    __syncthreads();
    int r = tid >> 2, q = tid & 3;
    int row = r0 + r;
    if (row >= N_NODES) return;
    float acc[8];
#pragma unroll
    for (int j = 0; j < 8; ++j) acc[j] = b[q * 8 + j];
    for (int f = 0; f < 108; ++f) {
        float a = Al[r][f];
#pragma unroll
        for (int j = 0; j < 8; ++j)
            acc[j] = fmaf(a, Wl[f * 32 + q * 8 + j], acc[j]);
    }
#pragma unroll
    for (int j = 0; j < 8; ++j) out[row * 32 + q * 8 + j] = acc[j];
}

// ---------------- launch ----------------

extern "C" void kernel_launch(void* const* d_in, const int* in_sizes, int n_in,
                              void* d_out, int out_size, void* d_ws, size_t ws_size,
                              hipStream_t stream) {
    const float* x      = (const float*)d_in[0];
    const int*   ei     = (const int*)d_in[1];
    const float* W1_1   = (const float*)d_in[2];
    // b1_1 / b1_2 cancel exactly under training-mode BN -> dropped.
    const float* g1_1   = (const float*)d_in[4];
    const float* be1_1  = (const float*)d_in[5];
    const float* W1_2   = (const float*)d_in[6];
    const float* g1_2   = (const float*)d_in[8];
    const float* be1_2  = (const float*)d_in[9];
    const float* gin_w1 = (const float*)d_in[10];
    const float* gin_b1 = (const float*)d_in[11];
    const float* gin_w2 = (const float*)d_in[12];
    const float* gin_b2 = (const float*)d_in[13];
    const float* g2     = (const float*)d_in[14];
    const float* be2    = (const float*)d_in[15];
    const float* W4     = (const float*)d_in[16];
    const float* b4     = (const float*)d_in[17];
    float* out = (float*)d_out;

    char* ws = (char*)d_ws;
    size_t off = 0;
    auto alloc = [&](size_t bytes) -> char* {
        char* p = ws + off;
        off = (off + bytes + 255) & ~(size_t)255;
        return p;
    };
    int*   cnt8  = (int*)alloc((size_t)8 * N_NODES * 4);
    int*   deg8  = (int*)alloc((size_t)8 * N_NODES * 4);   // reused as cur8
    size_t zend = off;
    int*   rp    = (int*)alloc((size_t)(N_NODES + 1) * 4);
    int*   rp8   = (int*)alloc((size_t)8 * N_NODES * 4);
    int*   bsum  = (int*)alloc(512 * 4);
    float* dis   = (float*)alloc((size_t)N_NODES * 4);
    int2*  csrw  = (int2*)alloc((size_t)N_EDGES * 8);
    float* ssA   = (float*)alloc(72 * 4);
    float* ssB   = (float*)alloc(72 * 4);
    float* ssC   = (float*)alloc(72 * 4);
    float* partials = (float*)alloc((size_t)6250 * 72 * 4);
    constexpr size_t NB36 = (size_t)N_NODES * 36 * 4;      // f32 [N,36]
    constexpr size_t NBBF = (size_t)N_NODES * 128;         // bf16 [N,64] rows (128B)
    uint2* xbf = (uint2*)alloc(NBBF);
    uint2* R0  = (uint2*)alloc(NBBF);
    uint2* R1  = (uint2*)alloc(NBBF);
    uint2* R2  = (uint2*)alloc(NBBF);
    float* X1  = (float*)alloc(NB36);
    float* X2  = (float*)alloc(NB36);
    float* X3  = (float*)alloc(NB36);
    if (off > ws_size) return;

    hipMemsetAsync(d_ws, 0, zend, stream);

    const int SCAN_BLKS = (N_NODES + 255) / 256;      // 391
    hist8_kernel<<<2048, 256, 0, stream>>>(ei, deg8, cnt8);
    scan1_kernel<<<SCAN_BLKS, 256, 0, stream>>>(cnt8, deg8, rp, bsum, dis);
    scan2_kernel<<<1, 512, 0, stream>>>(bsum, SCAN_BLKS);
    scan3_kernel<<<SCAN_BLKS, 256, 0, stream>>>(rp, bsum, cnt8, rp8);
    hipMemsetAsync(deg8, 0, (size_t)8 * N_NODES * 4, stream);
    fill8_kernel<<<2048, 256, 0, stream>>>(ei, rp8, deg8, dis, csrw);
    pack_x_kernel<<<(N_NODES * 16 + 255) / 256, 256, 0, stream>>>(x, xbf);

    const int STEP_BLKS = (N_NODES + 27) / 28;        // 3572
    const int GIN_BLKS  = (N_NODES + 15) / 16;        // 6250
    const int F3_BLKS   = (N_NODES + 63) / 64;        // 1563

    // ---- conv1_1 (Clenshaw, FI=64, A=x) ----
    cheb_step_kernel<64, 0, false, false, false, true><<<STEP_BLKS, 252, 0, stream>>>(
        rp, csrw, nullptr, nullptr, x, W1_1 + 7 * 2304, nullptr, R0, nullptr);
    cheb_step_kernel<64, 2, false, false, false, true><<<STEP_BLKS, 252, 0, stream>>>(
        rp, csrw, R0, nullptr, x, W1_1 + 6 * 2304, nullptr, R1, nullptr);
    cheb_step_kernel<64, 2, true, false, false, true><<<STEP_BLKS, 252, 0, stream>>>(
        rp, csrw, R1, R0, x, W1_1 + 5 * 2304, nullptr, R2, nullptr);
    cheb_step_kernel<64, 2, true, false, false, true><<<STEP_BLKS, 252, 0, stream>>>(
        rp, csrw, R2, R1, x, W1_1 + 4 * 2304, nullptr, R0, nullptr);
    cheb_step_kernel<64, 2, true, false, false, true><<<STEP_BLKS, 252, 0, stream>>>(
        rp, csrw, R0, R2, x, W1_1 + 3 * 2304, nullptr, R1, nullptr);
    cheb_step_kernel<64, 2, true, false, false, true><<<STEP_BLKS, 252, 0, stream>>>(
        rp, csrw, R1, R0, x, W1_1 + 2 * 2304, nullptr, R2, nullptr);
    cheb_step_kernel<64, 2, true, false, false, true><<<STEP_BLKS, 252, 0, stream>>>(
        rp, csrw, R2, R1, x, W1_1 + 1 * 2304, nullptr, R0, nullptr);
    cheb_step_kernel<64, 1, true, false, true, false><<<STEP_BLKS, 252, 0, stream>>>(
        rp, csrw, R0, R2, x, W1_1 + 0 * 2304, nullptr, X1, partials);
    finalize_kernel<<<36, 256, 0, stream>>>(partials, STEP_BLKS, g1_1, be1_1, ssA);

    // ---- conv1_2 (Clenshaw, FI=36, A=X1 with BN ssA) ----
    cheb_step_kernel<36, 0, false, true, false, true><<<STEP_BLKS, 252, 0, stream>>>(
        rp, csrw, nullptr, nullptr, X1, W1_2 + 7 * 1296, ssA, R0, nullptr);
    cheb_step_kernel<36, 2, false, true, false, true><<<STEP_BLKS, 252, 0, stream>>>(
        rp, csrw, R0, nullptr, X1, W1_2 + 6 * 1296, ssA, R1, nullptr);
    cheb_step_kernel<36, 2, true, true, false, true><<<STEP_BLKS, 252, 0, stream>>>(
        rp, csrw, R1, R0, X1, W1_2 + 5 * 1296, ssA, R2, nullptr);
    cheb_step_kernel<36, 2, true, true, false, true><<<STEP_BLKS, 252, 0, stream>>>(
        rp, csrw, R2, R1, X1, W1_2 + 4 * 1296, ssA, R0, nullptr);
    cheb_step_kernel<36, 2, true, true, false, true><<<STEP_BLKS, 252, 0, stream>>>(
        rp, csrw, R0, R2, X1, W1_2 + 3 * 1296, ssA, R1, nullptr);
    cheb_step_kernel<36, 2, true, true, false, true><<<STEP_BLKS, 252, 0, stream>>>(
        rp, csrw, R1, R0, X1, W1_2 + 2 * 1296, ssA, R2, nullptr);
    cheb_step_kernel<36, 2, true, true, false, true><<<STEP_BLKS, 252, 0, stream>>>(
        rp, csrw, R2, R1, X1, W1_2 + 1 * 1296, ssA, R0, nullptr);
    cheb_step_kernel<36, 1, true, true, true, false><<<STEP_BLKS, 252, 0, stream>>>(
        rp, csrw, R0, R2, X1, W1_2 + 0 * 1296, ssA, X2, partials);
    finalize_kernel<<<36, 256, 0, stream>>>(partials, STEP_BLKS, g1_2, be1_2, ssB);

    // ---- GIN ----
    gin_fused_kernel<<<GIN_BLKS, 256, 0, stream>>>(rp, csrw, x, xbf, gin_w1, gin_b1,
                                                   gin_w2, gin_b2, X3, partials);
    finalize_kernel<<<36, 256, 0, stream>>>(partials, GIN_BLKS, g2, be2, ssC);

    // ---- final concat GEMM ----
    fused3_kernel<<<F3_BLKS, 256, 0, stream>>>(X1, ssA, X2, ssB, X3, ssC, W4, b4, out);
}

// Round 6
// 1013.649 us; speedup vs baseline: 1.7191x; 1.1171x over previous
//
#include <hip/hip_runtime.h>

constexpr int N_NODES = 100000;
constexpr int N_EDGES = 1600000;
constexpr int NBK  = 391;    // buckets of 256 nodes (node >> 8)
constexpr int NBLK = 640;    // partition blocks
constexpr int CHUNK = 2500;  // edges per block: 640*2500 = 1.6M exactly
constexpr int LCNT = NBK * NBLK;            // 250240
constexpr int SCAN_BLKS = (LCNT + 255) / 256;  // 978

// ---------------- bf16 helpers (RNE) ----------------

__device__ __forceinline__ unsigned bf16pack(float a, float b) {
    unsigned ua = __float_as_uint(a), ub = __float_as_uint(b);
    ua += 0x7fffu + ((ua >> 16) & 1u);
    ub += 0x7fffu + ((ub >> 16) & 1u);
    return (ua >> 16) | (ub & 0xffff0000u);
}
__device__ __forceinline__ float bflo(unsigned p) { return __uint_as_float(p << 16); }
__device__ __forceinline__ float bfhi(unsigned p) { return __uint_as_float(p & 0xffff0000u); }

// ---------------- preprocessing: atomic-free two-level counting sort ----------

// P0: per-(bucket,block) counts for src and dst via LDS histograms.
__global__ __launch_bounds__(256) void part_count_kernel(
    const int* __restrict__ ei, int* __restrict__ cntD, int* __restrict__ cntS) {
    __shared__ int hd[NBK], hs[NBK];
    int tid = threadIdx.x;
    for (int i = tid; i < NBK; i += 256) { hd[i] = 0; hs[i] = 0; }
    __syncthreads();
    int e0 = blockIdx.x * CHUNK;
    for (int e = e0 + tid; e < e0 + CHUNK; e += 256) {
        int s = ei[e], d = ei[N_EDGES + e];
        atomicAdd(&hs[s >> 8], 1);
        atomicAdd(&hd[d >> 8], 1);
    }
    __syncthreads();
    for (int i = tid; i < NBK; i += 256) {
        cntD[i * NBLK + blockIdx.x] = hd[i];
        cntS[i * NBLK + blockIdx.x] = hs[i];
    }
}

// exclusive scan over length-L array (in-place safe), hierarchical
__global__ __launch_bounds__(256) void scanA_kernel(const int* __restrict__ in,
                                                    int* __restrict__ out,
                                                    int* __restrict__ bsum, int L) {
    __shared__ int sm[256];
    int i = blockIdx.x * 256 + threadIdx.x;
    int v = (i < L) ? in[i] : 0;
    sm[threadIdx.x] = v;
    __syncthreads();
    for (int off = 1; off < 256; off <<= 1) {
        int t = (threadIdx.x >= off) ? sm[threadIdx.x - off] : 0;
        __syncthreads();
        sm[threadIdx.x] += t;
        __syncthreads();
    }
    if (i < L) out[i] = sm[threadIdx.x] - v;
    if (threadIdx.x == 255) bsum[blockIdx.x] = sm[255];
}

__global__ __launch_bounds__(1024) void scanB_kernel(int* __restrict__ bsum, int nb) {
    __shared__ int sm[1024];
    int t = threadIdx.x;
    int v = (t < nb) ? bsum[t] : 0;
    sm[t] = v;
    __syncthreads();
    for (int off = 1; off < 1024; off <<= 1) {
        int u = (t >= off) ? sm[t - off] : 0;
        __syncthreads();
        sm[t] += u;
        __syncthreads();
    }
    if (t < nb) bsum[t] = sm[t] - v;
}

__global__ __launch_bounds__(256) void scanC_kernel(int* __restrict__ out,
                                                    const int* __restrict__ bsum, int L) {
    int i = blockIdx.x * 256 + threadIdx.x;
    if (i < L) out[i] += bsum[blockIdx.x];
}

// P2: scatter edges into dst-partition (src,dst) and src-partition (src).
// Positions from scanned per-(bucket,block) bases; LDS atomics only.
__global__ __launch_bounds__(256) void part_scatter_kernel(
    const int* __restrict__ ei, const int* __restrict__ scanD,
    const int* __restrict__ scanS, int2* __restrict__ edgepart,
    int* __restrict__ srcpart) {
    __shared__ int curD[NBK], curS[NBK];
    int tid = threadIdx.x;
    for (int i = tid; i < NBK; i += 256) {
        curD[i] = scanD[i * NBLK + blockIdx.x];
        curS[i] = scanS[i * NBLK + blockIdx.x];
    }
    __syncthreads();
    int e0 = blockIdx.x * CHUNK;
    for (int e = e0 + tid; e < e0 + CHUNK; e += 256) {
        int s = ei[e], d = ei[N_EDGES + e];
        int pd = atomicAdd(&curD[d >> 8], 1);
        edgepart[pd] = make_int2(s, d);
        int ps = atomicAdd(&curS[s >> 8], 1);
        srcpart[ps] = s;
    }
}

// P3-src: per-bucket degree count -> dis
__global__ __launch_bounds__(256) void deg_kernel(const int* __restrict__ srcpart,
                                                  const int* __restrict__ scanS,
                                                  float* __restrict__ dis) {
    __shared__ int cnt[256];
    int b = blockIdx.x, tid = threadIdx.x;
    cnt[tid] = 0;
    __syncthreads();
    int beg = scanS[b * NBLK];
    int end = (b + 1 < NBK) ? scanS[(b + 1) * NBLK] : N_EDGES;
    for (int j = beg + tid; j < end; j += 256)
        atomicAdd(&cnt[srcpart[j] & 255], 1);
    __syncthreads();
    int node = b * 256 + tid;
    if (node < N_NODES) dis[node] = cnt[tid] > 0 ? rsqrtf((float)cnt[tid]) : 0.f;
}

// P3-dst: per-bucket in-degree count -> rp (coalesced), then CSR fill with weights
__global__ __launch_bounds__(256) void csr_kernel(const int2* __restrict__ edgepart,
                                                  const int* __restrict__ scanD,
                                                  const float* __restrict__ dis,
                                                  int* __restrict__ rp,
                                                  int2* __restrict__ csrw) {
    __shared__ int cnt[256];
    __shared__ int lofs[256];
    __shared__ float disl[256];
    int b = blockIdx.x, tid = threadIdx.x;
    int beg = scanD[b * NBLK];
    int end = (b + 1 < NBK) ? scanD[(b + 1) * NBLK] : N_EDGES;
    int node = b * 256 + tid;
    cnt[tid] = 0;
    disl[tid] = (node < N_NODES) ? dis[node] : 0.f;
    __syncthreads();
    for (int j = beg + tid; j < end; j += 256)
        atomicAdd(&cnt[edgepart[j].y & 255], 1);
    __syncthreads();
    int v = cnt[tid];
    lofs[tid] = v;
    __syncthreads();
    for (int off = 1; off < 256; off <<= 1) {
        int t = (tid >= off) ? lofs[tid - off] : 0;
        __syncthreads();
        lofs[tid] += t;
        __syncthreads();
    }
    int myexc = lofs[tid] - v;
    if (node < N_NODES) rp[node] = beg + myexc;
    if (b == NBK - 1 && tid == 0) rp[N_NODES] = N_EDGES;
    __syncthreads();
    lofs[tid] = myexc;       // exclusive offsets for fill
    cnt[tid] = 0;
    __syncthreads();
    for (int j = beg + tid; j < end; j += 256) {
        int2 e = edgepart[j];
        int dl = e.y & 255;
        int pos = beg + lofs[dl] + atomicAdd(&cnt[dl], 1);
        csrw[pos] = make_int2(e.x, __float_as_int(-dis[e.x] * disl[dl]));
    }
}

// pack x [N,64] f32 -> bf16 (row = 128B = 1 cache line)
__global__ void pack_x_kernel(const float* __restrict__ x, uint2* __restrict__ xbf) {
    int i = blockIdx.x * blockDim.x + threadIdx.x;     // over N*16
    if (i >= N_NODES * 16) return;
    float4 v = ((const float4*)x)[i];
    xbf[i] = make_uint2(bf16pack(v.x, v.y), bf16pack(v.z, v.w));
}

// ---------------- fused Clenshaw step ----------------
// OUT[row] = SCALE * sum_j w_j*INb[src_j] + A'[row]@W - (HAS_B2 ? B2b[row] : 0)
// INb/B2b are bf16, row stride 16 uint2 (128B). SCALE==0 -> pure projection.
// A' = BN_A ? relu(ss*A+sh) : A.  OUT_BF16: write packed bf16, else f32.

template <int FI, int SCALE, bool HAS_B2, bool BN_A, bool FUSE_STATS, bool OUT_BF16>
__global__ __launch_bounds__(256) void cheb_step_kernel(
    const int* __restrict__ rp, const int2* __restrict__ csrw,
    const uint2* __restrict__ INb, const uint2* __restrict__ B2b,
    const float* __restrict__ A, const float* __restrict__ W,
    const float* __restrict__ ss, void* __restrict__ OUT,
    float* __restrict__ partials) {
    __shared__ float Wl[FI * 36];
    __shared__ float Atile[28][FI + 1];
    __shared__ float ls[72];
    int tid = threadIdx.x;                       // 252 threads = 28 rows x 9 lanes
    for (int i = tid; i < FI * 36; i += 252) Wl[i] = W[i];
    int r0 = blockIdx.x * 28;
    for (int i = tid; i < 28 * FI; i += 252) {
        int r = i / FI, f = i % FI;
        int row = r0 + r;
        float v = (row < N_NODES) ? A[row * FI + f] : 0.f;
        if (BN_A) v = fmaxf(fmaf(ss[f], v, ss[36 + f]), 0.f);
        Atile[r][f] = v;
    }
    if (FUSE_STATS && tid < 72) ls[tid] = 0.f;
    __syncthreads();
    int r = tid / 9, c = tid % 9;
    int row = r0 + r;
    bool valid = row < N_NODES;
    float ax = 0, ay = 0, az = 0, aw = 0;
    float bx = 0, by = 0, bz = 0, bw = 0;
    if (SCALE != 0 && valid) {
        int beg = rp[row], end = rp[row + 1];
        int j = beg;
        for (; j + 3 < end; j += 4) {            // 4 gathers in flight, 2 acc chains
            int2 e0 = csrw[j], e1 = csrw[j + 1], e2 = csrw[j + 2], e3 = csrw[j + 3];
            uint2 u0 = INb[e0.x * 16 + c];
            uint2 u1 = INb[e1.x * 16 + c];
            uint2 u2 = INb[e2.x * 16 + c];
            uint2 u3 = INb[e3.x * 16 + c];
            float w0 = __int_as_float(e0.y), w1 = __int_as_float(e1.y);
            float w2 = __int_as_float(e2.y), w3 = __int_as_float(e3.y);
            ax = fmaf(w0, bflo(u0.x), ax); ay = fmaf(w0, bfhi(u0.x), ay);
            az = fmaf(w0, bflo(u0.y), az); aw = fmaf(w0, bfhi(u0.y), aw);
            bx = fmaf(w1, bflo(u1.x), bx); by = fmaf(w1, bfhi(u1.x), by);
            bz = fmaf(w1, bflo(u1.y), bz); bw = fmaf(w1, bfhi(u1.y), bw);
            ax = fmaf(w2, bflo(u2.x), ax); ay = fmaf(w2, bfhi(u2.x), ay);
            az = fmaf(w2, bflo(u2.y), az); aw = fmaf(w2, bfhi(u2.y), aw);
            bx = fmaf(w3, bflo(u3.x), bx); by = fmaf(w3, bfhi(u3.x), by);
            bz = fmaf(w3, bflo(u3.y), bz); bw = fmaf(w3, bfhi(u3.y), bw);
        }
        for (; j < end; ++j) {
            int2 e = csrw[j];
            uint2 u = INb[e.x * 16 + c];
            float w = __int_as_float(e.y);
            ax = fmaf(w, bflo(u.x), ax); ay = fmaf(w, bfhi(u.x), ay);
            az = fmaf(w, bflo(u.y), az); aw = fmaf(w, bfhi(u.y), aw);
        }
        ax += bx; ay += by; az += bz; aw += bw;
    }
    float px = 0, py = 0, pz = 0, pw = 0;
    const float4* Wl4 = (const float4*)Wl;
#pragma unroll 4
    for (int f = 0; f < FI; ++f) {
        float a = Atile[r][f];
        float4 wv = Wl4[f * 9 + c];
        px = fmaf(a, wv.x, px); py = fmaf(a, wv.y, py);
        pz = fmaf(a, wv.z, pz); pw = fmaf(a, wv.w, pw);
    }
    const float S = (float)SCALE;
    float4 o;
    o.x = fmaf(S, ax, px); o.y = fmaf(S, ay, py);
    o.z = fmaf(S, az, pz); o.w = fmaf(S, aw, pw);
    if (valid) {
        if (HAS_B2) {
            uint2 u = B2b[row * 16 + c];
            o.x -= bflo(u.x); o.y -= bfhi(u.x);
            o.z -= bflo(u.y); o.w -= bfhi(u.y);
        }
        if (OUT_BF16) {
            ((uint2*)OUT)[row * 16 + c] =
                make_uint2(bf16pack(o.x, o.y), bf16pack(o.z, o.w));
        } else {
            ((float4*)OUT)[row * 9 + c] = o;
        }
        if (FUSE_STATS) {
            atomicAdd(&ls[c * 4 + 0], o.x); atomicAdd(&ls[36 + c * 4 + 0], o.x * o.x);
            atomicAdd(&ls[c * 4 + 1], o.y); atomicAdd(&ls[36 + c * 4 + 1], o.y * o.y);
            atomicAdd(&ls[c * 4 + 2], o.z); atomicAdd(&ls[36 + c * 4 + 2], o.z * o.z);
            atomicAdd(&ls[c * 4 + 3], o.w); atomicAdd(&ls[36 + c * 4 + 3], o.w * o.w);
        }
    }
    if (FUSE_STATS) {
        __syncthreads();
        if (tid < 72) partials[blockIdx.x * 72 + tid] = ls[tid];
    }
}

// ---------------- GIN mega-kernel ----------------

__global__ __launch_bounds__(256) void gin_fused_kernel(
    const int* __restrict__ rp, const int2* __restrict__ csrw,
    const float* __restrict__ X, const uint2* __restrict__ Xb,
    const float* __restrict__ w1, const float* __restrict__ b1,
    const float* __restrict__ w2, const float* __restrict__ b2,
    float* __restrict__ OUT, float* __restrict__ partials) {
    __shared__ float W1l[64 * 36];
    __shared__ float W2l[36 * 36];
    __shared__ float B1l[36], B2l[36];
    __shared__ float Ht[16][68];
    __shared__ float M1t[16][40];
    __shared__ float ls[72];
    int tid = threadIdx.x;                       // 256 = 16 rows x 16 lanes
    for (int i = tid; i < 64 * 36; i += 256) W1l[i] = w1[i];
    for (int i = tid; i < 36 * 36; i += 256) W2l[i] = w2[i];
    if (tid < 36) { B1l[tid] = b1[tid]; B2l[tid] = b2[tid]; }
    if (tid < 72) ls[tid] = 0.f;
    int r = tid >> 4, l = tid & 15;
    int row = blockIdx.x * 16 + r;
    bool valid = row < N_NODES;
    float hx = 0, hy = 0, hz = 0, hw = 0;
    float gx = 0, gy = 0, gz = 0, gw = 0;
    if (valid) {
        float4 self = ((const float4*)X)[row * 16 + l];
        hx = self.x; hy = self.y; hz = self.z; hw = self.w;
        int beg = rp[row], end = rp[row + 1];
        int j = beg;
        for (; j + 3 < end; j += 4) {
            int s0 = csrw[j].x, s1 = csrw[j + 1].x, s2 = csrw[j + 2].x, s3 = csrw[j + 3].x;
            uint2 u0 = Xb[s0 * 16 + l];
            uint2 u1 = Xb[s1 * 16 + l];
            uint2 u2 = Xb[s2 * 16 + l];
            uint2 u3 = Xb[s3 * 16 + l];
            hx += bflo(u0.x) + bflo(u1.x); hy += bfhi(u0.x) + bfhi(u1.x);
            hz += bflo(u0.y) + bflo(u1.y); hw += bfhi(u0.y) + bfhi(u1.y);
            gx += bflo(u2.x) + bflo(u3.x); gy += bfhi(u2.x) + bfhi(u3.x);
            gz += bflo(u2.y) + bflo(u3.y); gw += bfhi(u2.y) + bfhi(u3.y);
        }
        for (; j < end; ++j) {
            uint2 u = Xb[csrw[j].x * 16 + l];
            hx += bflo(u.x); hy += bfhi(u.x);
            hz += bflo(u.y); hw += bfhi(u.y);
        }
        hx += gx; hy += gy; hz += gz; hw += gw;
    }
    Ht[r][l * 4 + 0] = hx; Ht[r][l * 4 + 1] = hy;
    Ht[r][l * 4 + 2] = hz; Ht[r][l * 4 + 3] = hw;
    __syncthreads();
    float m1a = B1l[l], m1b = B1l[l + 16], m1c = (l < 4) ? B1l[l + 32] : 0.f;
#pragma unroll 4
    for (int f = 0; f < 64; ++f) {
        float a = Ht[r][f];
        m1a = fmaf(a, W1l[f * 36 + l], m1a);
        m1b = fmaf(a, W1l[f * 36 + l + 16], m1b);
        if (l < 4) m1c = fmaf(a, W1l[f * 36 + l + 32], m1c);
    }
    m1a = fmaxf(m1a, 0.f); m1b = fmaxf(m1b, 0.f); m1c = fmaxf(m1c, 0.f);
    M1t[r][l] = m1a; M1t[r][l + 16] = m1b;
    if (l < 4) M1t[r][l + 32] = m1c;
    __syncthreads();
    float m2a = B2l[l], m2b = B2l[l + 16], m2c = (l < 4) ? B2l[l + 32] : 0.f;
#pragma unroll 4
    for (int f = 0; f < 36; ++f) {
        float a = M1t[r][f];
        m2a = fmaf(a, W2l[f * 36 + l], m2a);
        m2b = fmaf(a, W2l[f * 36 + l + 16], m2b);
        if (l < 4) m2c = fmaf(a, W2l[f * 36 + l + 32], m2c);
    }
    m2a = fmaxf(m2a, 0.f); m2b = fmaxf(m2b, 0.f); m2c = fmaxf(m2c, 0.f);
    if (valid) {
        OUT[row * 36 + l] = m2a;
        OUT[row * 36 + l + 16] = m2b;
        if (l < 4) OUT[row * 36 + l + 32] = m2c;
        atomicAdd(&ls[l], m2a); atomicAdd(&ls[36 + l], m2a * m2a);
        atomicAdd(&ls[l + 16], m2b); atomicAdd(&ls[36 + l + 16], m2b * m2b);
        if (l < 4) { atomicAdd(&ls[l + 32], m2c); atomicAdd(&ls[36 + l + 32], m2c * m2c); }
    }
    __syncthreads();
    if (tid < 72) partials[blockIdx.x * 72 + tid] = ls[tid];
}

// ---------------- finalize: reduce partials -> BN scale/shift ----------------

__global__ __launch_bounds__(256) void finalize_kernel(
    const float* __restrict__ partials, int nb, const float* __restrict__ g,
    const float* __restrict__ be, float* __restrict__ ss) {
    __shared__ float rs[256], rq[256];
    int c = blockIdx.x;
    int t = threadIdx.x;
    float s = 0.f, q = 0.f;
    for (int i = t; i < nb; i += 256) {
        s += partials[i * 72 + c];
        q += partials[i * 72 + c + 36];
    }
    rs[t] = s; rq[t] = q;
    __syncthreads();
    for (int off = 128; off > 0; off >>= 1) {
        if (t < off) { rs[t] += rs[t + off]; rq[t] += rq[t + off]; }
        __syncthreads();
    }
    if (t == 0) {
        float m = rs[0] / (float)N_NODES;
        float v = rq[0] / (float)N_NODES - m * m;
        float sc = g[c] * rsqrtf(v + 1e-5f);
        ss[c] = sc;
        ss[36 + c] = be[c] - m * sc;
    }
}

// ---------------- final concat GEMM with BN folds ----------------

__global__ __launch_bounds__(256) void fused3_kernel(
    const float* __restrict__ X1, const float* __restrict__ ssA,
    const float* __restrict__ X2, const float* __restrict__ ssB,
    const float* __restrict__ X3, const float* __restrict__ ssC,
    const float* __restrict__ W, const float* __restrict__ b,
    float* __restrict__ out) {
    __shared__ float Wl[108 * 32];
    __shared__ float Al[64][109];
    int tid = threadIdx.x;
    for (int i = tid; i < 108 * 32; i += 256) Wl[i] = W[i];
    int r0 = blockIdx.x * 64;
    for (int i = tid; i < 64 * 108; i += 256) {
        int r = i / 108, f = i % 108;
        int row = r0 + r;
        float v = 0.f;
        if (row < N_NODES) {
            if (f < 36) {
                v = fmaxf(fmaf(ssA[f], X1[row * 36 + f], ssA[36 + f]), 0.f);
            } else if (f < 72) {
                int ff = f - 36;
                v = fmaxf(fmaf(ssB[ff], X2[row * 36 + ff], ssB[36 + ff]), 0.f);
            } else {
                int ff = f - 72;
                v = fmaf(ssC[ff], X3[row * 36 + ff], ssC[36 + ff]);
            }
        }
        Al[r][f] = v;
    }
    __syncthreads();
    int r = tid >> 2, q = tid & 3;
    int row = r0 + r;
    if (row >= N_NODES) return;
    float acc[8];
#pragma unroll
    for (int j = 0; j < 8; ++j) acc[j] = b[q * 8 + j];
    for (int f = 0; f < 108; ++f) {
        float a = Al[r][f];
#pragma unroll
        for (int j = 0; j < 8; ++j)
            acc[j] = fmaf(a, Wl[f * 32 + q * 8 + j], acc[j]);
    }
#pragma unroll
    for (int j = 0; j < 8; ++j) out[row * 32 + q * 8 + j] = acc[j];
}

// ---------------- launch ----------------

extern "C" void kernel_launch(void* const* d_in, const int* in_sizes, int n_in,
                              void* d_out, int out_size, void* d_ws, size_t ws_size,
                              hipStream_t stream) {
    const float* x      = (const float*)d_in[0];
    const int*   ei     = (const int*)d_in[1];
    const float* W1_1   = (const float*)d_in[2];
    // b1_1 / b1_2 cancel exactly under training-mode BN -> dropped.
    const float* g1_1   = (const float*)d_in[4];
    const float* be1_1  = (const float*)d_in[5];
    const float* W1_2   = (const float*)d_in[6];
    const float* g1_2   = (const float*)d_in[8];
    const float* be1_2  = (const float*)d_in[9];
    const float* gin_w1 = (const float*)d_in[10];
    const float* gin_b1 = (const float*)d_in[11];
    const float* gin_w2 = (const float*)d_in[12];
    const float* gin_b2 = (const float*)d_in[13];
    const float* g2     = (const float*)d_in[14];
    const float* be2    = (const float*)d_in[15];
    const float* W4     = (const float*)d_in[16];
    const float* b4     = (const float*)d_in[17];
    float* out = (float*)d_out;

    char* ws = (char*)d_ws;
    size_t off = 0;
    auto alloc = [&](size_t bytes) -> char* {
        char* p = ws + off;
        off = (off + bytes + 255) & ~(size_t)255;
        return p;
    };
    int*   cntD  = (int*)alloc((size_t)LCNT * 4);
    int*   cntS  = (int*)alloc((size_t)LCNT * 4);
    int*   bsum  = (int*)alloc(1024 * 4);
    int*   rp    = (int*)alloc((size_t)(N_NODES + 1) * 4);
    float* dis   = (float*)alloc((size_t)N_NODES * 4);
    int2*  edgepart = (int2*)alloc((size_t)N_EDGES * 8);
    int*   srcpart  = (int*)alloc((size_t)N_EDGES * 4);
    int2*  csrw  = (int2*)alloc((size_t)N_EDGES * 8);
    float* ssA   = (float*)alloc(72 * 4);
    float* ssB   = (float*)alloc(72 * 4);
    float* ssC   = (float*)alloc(72 * 4);
    float* partials = (float*)alloc((size_t)6250 * 72 * 4);
    constexpr size_t NB36 = (size_t)N_NODES * 36 * 4;      // f32 [N,36]
    constexpr size_t NBBF = (size_t)N_NODES * 128;         // bf16 [N,64] rows (128B)
    uint2* xbf = (uint2*)alloc(NBBF);
    uint2* R0  = (uint2*)alloc(NBBF);
    uint2* R1  = (uint2*)alloc(NBBF);
    uint2* R2  = (uint2*)alloc(NBBF);
    float* X1  = (float*)alloc(NB36);
    float* X2  = (float*)alloc(NB36);
    float* X3  = (float*)alloc(NB36);
    if (off > ws_size) return;

    // ---- preprocessing: counting-sort CSR build (no global atomics) ----
    part_count_kernel<<<NBLK, 256, 0, stream>>>(ei, cntD, cntS);
    scanA_kernel<<<SCAN_BLKS, 256, 0, stream>>>(cntD, cntD, bsum, LCNT);
    scanB_kernel<<<1, 1024, 0, stream>>>(bsum, SCAN_BLKS);
    scanC_kernel<<<SCAN_BLKS, 256, 0, stream>>>(cntD, bsum, LCNT);
    scanA_kernel<<<SCAN_BLKS, 256, 0, stream>>>(cntS, cntS, bsum, LCNT);
    scanB_kernel<<<1, 1024, 0, stream>>>(bsum, SCAN_BLKS);
    scanC_kernel<<<SCAN_BLKS, 256, 0, stream>>>(cntS, bsum, LCNT);
    part_scatter_kernel<<<NBLK, 256, 0, stream>>>(ei, cntD, cntS, edgepart, srcpart);
    deg_kernel<<<NBK, 256, 0, stream>>>(srcpart, cntS, dis);
    csr_kernel<<<NBK, 256, 0, stream>>>(edgepart, cntD, dis, rp, csrw);
    pack_x_kernel<<<(N_NODES * 16 + 255) / 256, 256, 0, stream>>>(x, xbf);

    const int STEP_BLKS = (N_NODES + 27) / 28;        // 3572
    const int GIN_BLKS  = (N_NODES + 15) / 16;        // 6250
    const int F3_BLKS   = (N_NODES + 63) / 64;        // 1563

    // ---- conv1_1 (Clenshaw, FI=64, A=x) ----
    cheb_step_kernel<64, 0, false, false, false, true><<<STEP_BLKS, 252, 0, stream>>>(
        rp, csrw, nullptr, nullptr, x, W1_1 + 7 * 2304, nullptr, R0, nullptr);
    cheb_step_kernel<64, 2, false, false, false, true><<<STEP_BLKS, 252, 0, stream>>>(
        rp, csrw, R0, nullptr, x, W1_1 + 6 * 2304, nullptr, R1, nullptr);
    cheb_step_kernel<64, 2, true, false, false, true><<<STEP_BLKS, 252, 0, stream>>>(
        rp, csrw, R1, R0, x, W1_1 + 5 * 2304, nullptr, R2, nullptr);
    cheb_step_kernel<64, 2, true, false, false, true><<<STEP_BLKS, 252, 0, stream>>>(
        rp, csrw, R2, R1, x, W1_1 + 4 * 2304, nullptr, R0, nullptr);
    cheb_step_kernel<64, 2, true, false, false, true><<<STEP_BLKS, 252, 0, stream>>>(
        rp, csrw, R0, R2, x, W1_1 + 3 * 2304, nullptr, R1, nullptr);
    cheb_step_kernel<64, 2, true, false, false, true><<<STEP_BLKS, 252, 0, stream>>>(
        rp, csrw, R1, R0, x, W1_1 + 2 * 2304, nullptr, R2, nullptr);
    cheb_step_kernel<64, 2, true, false, false, true><<<STEP_BLKS, 252, 0, stream>>>(
        rp, csrw, R2, R1, x, W1_1 + 1 * 2304, nullptr, R0, nullptr);
    cheb_step_kernel<64, 1, true, false, true, false><<<STEP_BLKS, 252, 0, stream>>>(
        rp, csrw, R0, R2, x, W1_1 + 0 * 2304, nullptr, X1, partials);
    finalize_kernel<<<36, 256, 0, stream>>>(partials, STEP_BLKS, g1_1, be1_1, ssA);

    // ---- conv1_2 (Clenshaw, FI=36, A=X1 with BN ssA) ----
    cheb_step_kernel<36, 0, false, true, false, true><<<STEP_BLKS, 252, 0, stream>>>(
        rp, csrw, nullptr, nullptr, X1, W1_2 + 7 * 1296, ssA, R0, nullptr);
    cheb_step_kernel<36, 2, false, true, false, true><<<STEP_BLKS, 252, 0, stream>>>(
        rp, csrw, R0, nullptr, X1, W1_2 + 6 * 1296, ssA, R1, nullptr);
    cheb_step_kernel<36, 2, true, true, false, true><<<STEP_BLKS, 252, 0, stream>>>(
        rp, csrw, R1, R0, X1, W1_2 + 5 * 1296, ssA, R2, nullptr);
    cheb_step_kernel<36, 2, true, true, false, true><<<STEP_BLKS, 252, 0, stream>>>(
        rp, csrw, R2, R1, X1, W1_2 + 4 * 1296, ssA, R0, nullptr);
    cheb_step_kernel<36, 2, true, true, false, true><<<STEP_BLKS, 252, 0, stream>>>(
        rp, csrw, R0, R2, X1, W1_2 + 3 * 1296, ssA, R1, nullptr);
    cheb_step_kernel<36, 2, true, true, false, true><<<STEP_BLKS, 252, 0, stream>>>(
        rp, csrw, R1, R0, X1, W1_2 + 2 * 1296, ssA, R2, nullptr);
    cheb_step_kernel<36, 2, true, true, false, true><<<STEP_BLKS, 252, 0, stream>>>(
        rp, csrw, R2, R1, X1, W1_2 + 1 * 1296, ssA, R0, nullptr);
    cheb_step_kernel<36, 1, true, true, true, false><<<STEP_BLKS, 252, 0, stream>>>(
        rp, csrw, R0, R2, X1, W1_2 + 0 * 1296, ssA, X2, partials);
    finalize_kernel<<<36, 256, 0, stream>>>(partials, STEP_BLKS, g1_2, be1_2, ssB);

    // ---- GIN ----
    gin_fused_kernel<<<GIN_BLKS, 256, 0, stream>>>(rp, csrw, x, xbf, gin_w1, gin_b1,
                                                   gin_w2, gin_b2, X3, partials);
    finalize_kernel<<<36, 256, 0, stream>>>(partials, GIN_BLKS, g2, be2, ssC);

    // ---- final concat GEMM ----
    fused3_kernel<<<F3_BLKS, 256, 0, stream>>>(X1, ssA, X2, ssB, X3, ssC, W4, b4, out);
}

// Round 7
// 989.798 us; speedup vs baseline: 1.7605x; 1.0241x over previous
//
#include <hip/hip_runtime.h>

constexpr int N_NODES = 100000;
constexpr int N_EDGES = 1600000;
constexpr int NBK  = 391;    // buckets of 256 nodes (node >> 8)
constexpr int NBLK = 640;    // partition blocks
constexpr int CHUNK = 2500;  // edges per block: 640*2500 = 1.6M exactly
constexpr int LCNT = NBK * NBLK;            // 250240
constexpr int SCAN_BLKS = (LCNT + 255) / 256;  // 978

// ---------------- bf16 helpers (RNE) ----------------

__device__ __forceinline__ unsigned bf16pack(float a, float b) {
    unsigned ua = __float_as_uint(a), ub = __float_as_uint(b);
    ua += 0x7fffu + ((ua >> 16) & 1u);
    ub += 0x7fffu + ((ub >> 16) & 1u);
    return (ua >> 16) | (ub & 0xffff0000u);
}
__device__ __forceinline__ float bflo(unsigned p) { return __uint_as_float(p << 16); }
__device__ __forceinline__ float bfhi(unsigned p) { return __uint_as_float(p & 0xffff0000u); }

// ---------------- preprocessing: atomic-free two-level counting sort ----------

__global__ __launch_bounds__(256) void part_count_kernel(
    const int* __restrict__ ei, int* __restrict__ cntD, int* __restrict__ cntS) {
    __shared__ int hd[NBK], hs[NBK];
    int tid = threadIdx.x;
    for (int i = tid; i < NBK; i += 256) { hd[i] = 0; hs[i] = 0; }
    __syncthreads();
    int e0 = blockIdx.x * CHUNK;
    for (int e = e0 + tid; e < e0 + CHUNK; e += 256) {
        int s = ei[e], d = ei[N_EDGES + e];
        atomicAdd(&hs[s >> 8], 1);
        atomicAdd(&hd[d >> 8], 1);
    }
    __syncthreads();
    for (int i = tid; i < NBK; i += 256) {
        cntD[i * NBLK + blockIdx.x] = hd[i];
        cntS[i * NBLK + blockIdx.x] = hs[i];
    }
}

__global__ __launch_bounds__(256) void scanA_kernel(const int* __restrict__ in,
                                                    int* __restrict__ out,
                                                    int* __restrict__ bsum, int L) {
    __shared__ int sm[256];
    int i = blockIdx.x * 256 + threadIdx.x;
    int v = (i < L) ? in[i] : 0;
    sm[threadIdx.x] = v;
    __syncthreads();
    for (int off = 1; off < 256; off <<= 1) {
        int t = (threadIdx.x >= off) ? sm[threadIdx.x - off] : 0;
        __syncthreads();
        sm[threadIdx.x] += t;
        __syncthreads();
    }
    if (i < L) out[i] = sm[threadIdx.x] - v;
    if (threadIdx.x == 255) bsum[blockIdx.x] = sm[255];
}

__global__ __launch_bounds__(1024) void scanB_kernel(int* __restrict__ bsum, int nb) {
    __shared__ int sm[1024];
    int t = threadIdx.x;
    int v = (t < nb) ? bsum[t] : 0;
    sm[t] = v;
    __syncthreads();
    for (int off = 1; off < 1024; off <<= 1) {
        int u = (t >= off) ? sm[t - off] : 0;
        __syncthreads();
        sm[t] += u;
        __syncthreads();
    }
    if (t < nb) bsum[t] = sm[t] - v;
}

__global__ __launch_bounds__(256) void scanC_kernel(int* __restrict__ out,
                                                    const int* __restrict__ bsum, int L) {
    int i = blockIdx.x * 256 + threadIdx.x;
    if (i < L) out[i] += bsum[blockIdx.x];
}

__global__ __launch_bounds__(256) void part_scatter_kernel(
    const int* __restrict__ ei, const int* __restrict__ scanD,
    const int* __restrict__ scanS, int2* __restrict__ edgepart,
    int* __restrict__ srcpart) {
    __shared__ int curD[NBK], curS[NBK];
    int tid = threadIdx.x;
    for (int i = tid; i < NBK; i += 256) {
        curD[i] = scanD[i * NBLK + blockIdx.x];
        curS[i] = scanS[i * NBLK + blockIdx.x];
    }
    __syncthreads();
    int e0 = blockIdx.x * CHUNK;
    for (int e = e0 + tid; e < e0 + CHUNK; e += 256) {
        int s = ei[e], d = ei[N_EDGES + e];
        int pd = atomicAdd(&curD[d >> 8], 1);
        edgepart[pd] = make_int2(s, d);
        int ps = atomicAdd(&curS[s >> 8], 1);
        srcpart[ps] = s;
    }
}

__global__ __launch_bounds__(256) void deg_kernel(const int* __restrict__ srcpart,
                                                  const int* __restrict__ scanS,
                                                  float* __restrict__ dis) {
    __shared__ int cnt[256];
    int b = blockIdx.x, tid = threadIdx.x;
    cnt[tid] = 0;
    __syncthreads();
    int beg = scanS[b * NBLK];
    int end = (b + 1 < NBK) ? scanS[(b + 1) * NBLK] : N_EDGES;
    for (int j = beg + tid; j < end; j += 256)
        atomicAdd(&cnt[srcpart[j] & 255], 1);
    __syncthreads();
    int node = b * 256 + tid;
    if (node < N_NODES) dis[node] = cnt[tid] > 0 ? rsqrtf((float)cnt[tid]) : 0.f;
}

__global__ __launch_bounds__(256) void csr_kernel(const int2* __restrict__ edgepart,
                                                  const int* __restrict__ scanD,
                                                  const float* __restrict__ dis,
                                                  int* __restrict__ rp,
                                                  int2* __restrict__ csrw) {
    __shared__ int cnt[256];
    __shared__ int lofs[256];
    __shared__ float disl[256];
    int b = blockIdx.x, tid = threadIdx.x;
    int beg = scanD[b * NBLK];
    int end = (b + 1 < NBK) ? scanD[(b + 1) * NBLK] : N_EDGES;
    int node = b * 256 + tid;
    cnt[tid] = 0;
    disl[tid] = (node < N_NODES) ? dis[node] : 0.f;
    __syncthreads();
    for (int j = beg + tid; j < end; j += 256)
        atomicAdd(&cnt[edgepart[j].y & 255], 1);
    __syncthreads();
    int v = cnt[tid];
    lofs[tid] = v;
    __syncthreads();
    for (int off = 1; off < 256; off <<= 1) {
        int t = (tid >= off) ? lofs[tid - off] : 0;
        __syncthreads();
        lofs[tid] += t;
        __syncthreads();
    }
    int myexc = lofs[tid] - v;
    if (node < N_NODES) rp[node] = beg + myexc;
    if (b == NBK - 1 && tid == 0) rp[N_NODES] = N_EDGES;
    __syncthreads();
    lofs[tid] = myexc;
    cnt[tid] = 0;
    __syncthreads();
    for (int j = beg + tid; j < end; j += 256) {
        int2 e = edgepart[j];
        int dl = e.y & 255;
        int pos = beg + lofs[dl] + atomicAdd(&cnt[dl], 1);
        csrw[pos] = make_int2(e.x, __float_as_int(-dis[e.x] * disl[dl]));
    }
}

// pack x [N,64] f32 -> bf16 (row = 128B = 1 cache line)
__global__ void pack_x_kernel(const float* __restrict__ x, uint2* __restrict__ xbf) {
    int i = blockIdx.x * blockDim.x + threadIdx.x;     // over N*16
    if (i >= N_NODES * 16) return;
    float4 v = ((const float4*)x)[i];
    xbf[i] = make_uint2(bf16pack(v.x, v.y), bf16pack(v.z, v.w));
}

// ---------------- fused Clenshaw step ----------------
// OUT[row] = SCALE * sum_j w_j*INb[src_j] + A'[row]@W - (HAS_B2 ? B2b[row] : 0)
// Gather loop: unroll x8, 4 independent accumulator chains (~8 loads in flight).

template <int FI, int SCALE, bool HAS_B2, bool BN_A, bool FUSE_STATS, bool OUT_BF16>
__global__ __launch_bounds__(256) void cheb_step_kernel(
    const int* __restrict__ rp, const int2* __restrict__ csrw,
    const uint2* __restrict__ INb, const uint2* __restrict__ B2b,
    const float* __restrict__ A, const float* __restrict__ W,
    const float* __restrict__ ss, void* __restrict__ OUT,
    float* __restrict__ partials) {
    __shared__ float Wl[FI * 36];
    __shared__ float Atile[28][FI + 1];
    __shared__ float ls[72];
    int tid = threadIdx.x;                       // 252 threads = 28 rows x 9 lanes
    for (int i = tid; i < FI * 36; i += 252) Wl[i] = W[i];
    int r0 = blockIdx.x * 28;
    for (int i = tid; i < 28 * FI; i += 252) {
        int r = i / FI, f = i % FI;
        int row = r0 + r;
        float v = (row < N_NODES) ? A[row * FI + f] : 0.f;
        if (BN_A) v = fmaxf(fmaf(ss[f], v, ss[36 + f]), 0.f);
        Atile[r][f] = v;
    }
    if (FUSE_STATS && tid < 72) ls[tid] = 0.f;
    __syncthreads();
    int r = tid / 9, c = tid % 9;
    int row = r0 + r;
    bool valid = row < N_NODES;
    float ax = 0, ay = 0, az = 0, aw = 0;
    float bx = 0, by = 0, bz = 0, bw = 0;
    float cx = 0, cy = 0, cz = 0, cw = 0;
    float dx = 0, dy = 0, dz = 0, dw = 0;
    if (SCALE != 0 && valid) {
        int beg = rp[row], end = rp[row + 1];
        int j = beg;
        for (; j + 7 < end; j += 8) {
            int2 e0 = csrw[j],     e1 = csrw[j + 1], e2 = csrw[j + 2], e3 = csrw[j + 3];
            int2 e4 = csrw[j + 4], e5 = csrw[j + 5], e6 = csrw[j + 6], e7 = csrw[j + 7];
            uint2 u0 = INb[e0.x * 16 + c];
            uint2 u1 = INb[e1.x * 16 + c];
            uint2 u2 = INb[e2.x * 16 + c];
            uint2 u3 = INb[e3.x * 16 + c];
            uint2 u4 = INb[e4.x * 16 + c];
            uint2 u5 = INb[e5.x * 16 + c];
            uint2 u6 = INb[e6.x * 16 + c];
            uint2 u7 = INb[e7.x * 16 + c];
            float w0 = __int_as_float(e0.y), w1 = __int_as_float(e1.y);
            float w2 = __int_as_float(e2.y), w3 = __int_as_float(e3.y);
            float w4 = __int_as_float(e4.y), w5 = __int_as_float(e5.y);
            float w6 = __int_as_float(e6.y), w7 = __int_as_float(e7.y);
            ax = fmaf(w0, bflo(u0.x), ax); ay = fmaf(w0, bfhi(u0.x), ay);
            az = fmaf(w0, bflo(u0.y), az); aw = fmaf(w0, bfhi(u0.y), aw);
            bx = fmaf(w1, bflo(u1.x), bx); by = fmaf(w1, bfhi(u1.x), by);
            bz = fmaf(w1, bflo(u1.y), bz); bw = fmaf(w1, bfhi(u1.y), bw);
            cx = fmaf(w2, bflo(u2.x), cx); cy = fmaf(w2, bfhi(u2.x), cy);
            cz = fmaf(w2, bflo(u2.y), cz); cw = fmaf(w2, bfhi(u2.y), cw);
            dx = fmaf(w3, bflo(u3.x), dx); dy = fmaf(w3, bfhi(u3.x), dy);
            dz = fmaf(w3, bflo(u3.y), dz); dw = fmaf(w3, bfhi(u3.y), dw);
            ax = fmaf(w4, bflo(u4.x), ax); ay = fmaf(w4, bfhi(u4.x), ay);
            az = fmaf(w4, bflo(u4.y), az); aw = fmaf(w4, bfhi(u4.y), aw);
            bx = fmaf(w5, bflo(u5.x), bx); by = fmaf(w5, bfhi(u5.x), by);
            bz = fmaf(w5, bflo(u5.y), bz); bw = fmaf(w5, bfhi(u5.y), bw);
            cx = fmaf(w6, bflo(u6.x), cx); cy = fmaf(w6, bfhi(u6.x), cy);
            cz = fmaf(w6, bflo(u6.y), cz); cw = fmaf(w6, bfhi(u6.y), cw);
            dx = fmaf(w7, bflo(u7.x), dx); dy = fmaf(w7, bfhi(u7.x), dy);
            dz = fmaf(w7, bflo(u7.y), dz); dw = fmaf(w7, bfhi(u7.y), dw);
        }
        for (; j + 3 < end; j += 4) {
            int2 e0 = csrw[j], e1 = csrw[j + 1], e2 = csrw[j + 2], e3 = csrw[j + 3];
            uint2 u0 = INb[e0.x * 16 + c];
            uint2 u1 = INb[e1.x * 16 + c];
            uint2 u2 = INb[e2.x * 16 + c];
            uint2 u3 = INb[e3.x * 16 + c];
            float w0 = __int_as_float(e0.y), w1 = __int_as_float(e1.y);
            float w2 = __int_as_float(e2.y), w3 = __int_as_float(e3.y);
            ax = fmaf(w0, bflo(u0.x), ax); ay = fmaf(w0, bfhi(u0.x), ay);
            az = fmaf(w0, bflo(u0.y), az); aw = fmaf(w0, bfhi(u0.y), aw);
            bx = fmaf(w1, bflo(u1.x), bx); by = fmaf(w1, bfhi(u1.x), by);
            bz = fmaf(w1, bflo(u1.y), bz); bw = fmaf(w1, bfhi(u1.y), bw);
            cx = fmaf(w2, bflo(u2.x), cx); cy = fmaf(w2, bfhi(u2.x), cy);
            cz = fmaf(w2, bflo(u2.y), cz); cw = fmaf(w2, bfhi(u2.y), cw);
            dx = fmaf(w3, bflo(u3.x), dx); dy = fmaf(w3, bfhi(u3.x), dy);
            dz = fmaf(w3, bflo(u3.y), dz); dw = fmaf(w3, bfhi(u3.y), dw);
        }
        for (; j < end; ++j) {
            int2 e = csrw[j];
            uint2 u = INb[e.x * 16 + c];
            float w = __int_as_float(e.y);
            ax = fmaf(w, bflo(u.x), ax); ay = fmaf(w, bfhi(u.x), ay);
            az = fmaf(w, bflo(u.y), az); aw = fmaf(w, bfhi(u.y), aw);
        }
        ax += bx + cx + dx; ay += by + cy + dy;
        az += bz + cz + dz; aw += bw + cw + dw;
    }
    float px = 0, py = 0, pz = 0, pw = 0;
    const float4* Wl4 = (const float4*)Wl;
#pragma unroll 4
    for (int f = 0; f < FI; ++f) {
        float a = Atile[r][f];
        float4 wv = Wl4[f * 9 + c];
        px = fmaf(a, wv.x, px); py = fmaf(a, wv.y, py);
        pz = fmaf(a, wv.z, pz); pw = fmaf(a, wv.w, pw);
    }
    const float S = (float)SCALE;
    float4 o;
    o.x = fmaf(S, ax, px); o.y = fmaf(S, ay, py);
    o.z = fmaf(S, az, pz); o.w = fmaf(S, aw, pw);
    if (valid) {
        if (HAS_B2) {
            uint2 u = B2b[row * 16 + c];
            o.x -= bflo(u.x); o.y -= bfhi(u.x);
            o.z -= bflo(u.y); o.w -= bfhi(u.y);
        }
        if (OUT_BF16) {
            ((uint2*)OUT)[row * 16 + c] =
                make_uint2(bf16pack(o.x, o.y), bf16pack(o.z, o.w));
        } else {
            ((float4*)OUT)[row * 9 + c] = o;
        }
        if (FUSE_STATS) {
            atomicAdd(&ls[c * 4 + 0], o.x); atomicAdd(&ls[36 + c * 4 + 0], o.x * o.x);
            atomicAdd(&ls[c * 4 + 1], o.y); atomicAdd(&ls[36 + c * 4 + 1], o.y * o.y);
            atomicAdd(&ls[c * 4 + 2], o.z); atomicAdd(&ls[36 + c * 4 + 2], o.z * o.z);
            atomicAdd(&ls[c * 4 + 3], o.w); atomicAdd(&ls[36 + c * 4 + 3], o.w * o.w);
        }
    }
    if (FUSE_STATS) {
        __syncthreads();
        if (tid < 72) partials[blockIdx.x * 72 + tid] = ls[tid];
    }
}

// ---------------- GIN mega-kernel ----------------
// h = xbf[row] + sum xbf[src]; OUT = relu(relu(h@w1+b1)@w2+b2); + stats partials

__global__ __launch_bounds__(256) void gin_fused_kernel(
    const int* __restrict__ rp, const int2* __restrict__ csrw,
    const uint2* __restrict__ Xb,
    const float* __restrict__ w1, const float* __restrict__ b1,
    const float* __restrict__ w2, const float* __restrict__ b2,
    float* __restrict__ OUT, float* __restrict__ partials) {
    __shared__ float W1l[64 * 36];
    __shared__ float W2l[36 * 36];
    __shared__ float B1l[36], B2l[36];
    __shared__ float Ht[16][68];
    __shared__ float M1t[16][40];
    __shared__ float ls[72];
    int tid = threadIdx.x;                       // 256 = 16 rows x 16 lanes
    for (int i = tid; i < 64 * 36; i += 256) W1l[i] = w1[i];
    for (int i = tid; i < 36 * 36; i += 256) W2l[i] = w2[i];
    if (tid < 36) { B1l[tid] = b1[tid]; B2l[tid] = b2[tid]; }
    if (tid < 72) ls[tid] = 0.f;
    int r = tid >> 4, l = tid & 15;
    int row = blockIdx.x * 16 + r;
    bool valid = row < N_NODES;
    float hx = 0, hy = 0, hz = 0, hw = 0;
    float gx = 0, gy = 0, gz = 0, gw = 0;
    float px = 0, py = 0, pz = 0, pw = 0;
    float qx = 0, qy = 0, qz = 0, qw = 0;
    if (valid) {
        uint2 us = Xb[row * 16 + l];
        hx = bflo(us.x); hy = bfhi(us.x); hz = bflo(us.y); hw = bfhi(us.y);
        int beg = rp[row], end = rp[row + 1];
        int j = beg;
        for (; j + 7 < end; j += 8) {
            int s0 = csrw[j].x,     s1 = csrw[j + 1].x, s2 = csrw[j + 2].x, s3 = csrw[j + 3].x;
            int s4 = csrw[j + 4].x, s5 = csrw[j + 5].x, s6 = csrw[j + 6].x, s7 = csrw[j + 7].x;
            uint2 u0 = Xb[s0 * 16 + l];
            uint2 u1 = Xb[s1 * 16 + l];
            uint2 u2 = Xb[s2 * 16 + l];
            uint2 u3 = Xb[s3 * 16 + l];
            uint2 u4 = Xb[s4 * 16 + l];
            uint2 u5 = Xb[s5 * 16 + l];
            uint2 u6 = Xb[s6 * 16 + l];
            uint2 u7 = Xb[s7 * 16 + l];
            hx += bflo(u0.x) + bflo(u4.x); hy += bfhi(u0.x) + bfhi(u4.x);
            hz += bflo(u0.y) + bflo(u4.y); hw += bfhi(u0.y) + bfhi(u4.y);
            gx += bflo(u1.x) + bflo(u5.x); gy += bfhi(u1.x) + bfhi(u5.x);
            gz += bflo(u1.y) + bflo(u5.y); gw += bfhi(u1.y) + bfhi(u5.y);
            px += bflo(u2.x) + bflo(u6.x); py += bfhi(u2.x) + bfhi(u6.x);
            pz += bflo(u2.y) + bflo(u6.y); pw += bfhi(u2.y) + bfhi(u6.y);
            qx += bflo(u3.x) + bflo(u7.x); qy += bfhi(u3.x) + bfhi(u7.x);
            qz += bflo(u3.y) + bflo(u7.y); qw += bfhi(u3.y) + bfhi(u7.y);
        }
        for (; j + 3 < end; j += 4) {
            int s0 = csrw[j].x, s1 = csrw[j + 1].x, s2 = csrw[j + 2].x, s3 = csrw[j + 3].x;
            uint2 u0 = Xb[s0 * 16 + l];
            uint2 u1 = Xb[s1 * 16 + l];
            uint2 u2 = Xb[s2 * 16 + l];
            uint2 u3 = Xb[s3 * 16 + l];
            hx += bflo(u0.x); hy += bfhi(u0.x); hz += bflo(u0.y); hw += bfhi(u0.y);
            gx += bflo(u1.x); gy += bfhi(u1.x); gz += bflo(u1.y); gw += bfhi(u1.y);
            px += bflo(u2.x); py += bfhi(u2.x); pz += bflo(u2.y); pw += bfhi(u2.y);
            qx += bflo(u3.x); qy += bfhi(u3.x); qz += bflo(u3.y); qw += bfhi(u3.y);
        }
        for (; j < end; ++j) {
            uint2 u = Xb[csrw[j].x * 16 + l];
            hx += bflo(u.x); hy += bfhi(u.x);
            hz += bflo(u.y); hw += bfhi(u.y);
        }
        hx += gx + px + qx; hy += gy + py + qy;
        hz += gz + pz + qz; hw += gw + pw + qw;
    }
    Ht[r][l * 4 + 0] = hx; Ht[r][l * 4 + 1] = hy;
    Ht[r][l * 4 + 2] = hz; Ht[r][l * 4 + 3] = hw;
    __syncthreads();
    float m1a = B1l[l], m1b = B1l[l + 16], m1c = (l < 4) ? B1l[l + 32] : 0.f;
#pragma unroll 4
    for (int f = 0; f < 64; ++f) {
        float a = Ht[r][f];
        m1a = fmaf(a, W1l[f * 36 + l], m1a);
        m1b = fmaf(a, W1l[f * 36 + l + 16], m1b);
        if (l < 4) m1c = fmaf(a, W1l[f * 36 + l + 32], m1c);
    }
    m1a = fmaxf(m1a, 0.f); m1b = fmaxf(m1b, 0.f); m1c = fmaxf(m1c, 0.f);
    M1t[r][l] = m1a; M1t[r][l + 16] = m1b;
    if (l < 4) M1t[r][l + 32] = m1c;
    __syncthreads();
    float m2a = B2l[l], m2b = B2l[l + 16], m2c = (l < 4) ? B2l[l + 32] : 0.f;
#pragma unroll 4
    for (int f = 0; f < 36; ++f) {
        float a = M1t[r][f];
        m2a = fmaf(a, W2l[f * 36 + l], m2a);
        m2b = fmaf(a, W2l[f * 36 + l + 16], m2b);
        if (l < 4) m2c = fmaf(a, W2l[f * 36 + l + 32], m2c);
    }
    m2a = fmaxf(m2a, 0.f); m2b = fmaxf(m2b, 0.f); m2c = fmaxf(m2c, 0.f);
    if (valid) {
        OUT[row * 36 + l] = m2a;
        OUT[row * 36 + l + 16] = m2b;
        if (l < 4) OUT[row * 36 + l + 32] = m2c;
        atomicAdd(&ls[l], m2a); atomicAdd(&ls[36 + l], m2a * m2a);
        atomicAdd(&ls[l + 16], m2b); atomicAdd(&ls[36 + l + 16], m2b * m2b);
        if (l < 4) { atomicAdd(&ls[l + 32], m2c); atomicAdd(&ls[36 + l + 32], m2c * m2c); }
    }
    __syncthreads();
    if (tid < 72) partials[blockIdx.x * 72 + tid] = ls[tid];
}

// ---------------- finalize: reduce partials -> BN scale/shift ----------------

__global__ __launch_bounds__(256) void finalize_kernel(
    const float* __restrict__ partials, int nb, const float* __restrict__ g,
    const float* __restrict__ be, float* __restrict__ ss) {
    __shared__ float rs[256], rq[256];
    int c = blockIdx.x;
    int t = threadIdx.x;
    float s = 0.f, q = 0.f;
    for (int i = t; i < nb; i += 256) {
        s += partials[i * 72 + c];
        q += partials[i * 72 + c + 36];
    }
    rs[t] = s; rq[t] = q;
    __syncthreads();
    for (int off = 128; off > 0; off >>= 1) {
        if (t < off) { rs[t] += rs[t + off]; rq[t] += rq[t + off]; }
        __syncthreads();
    }
    if (t == 0) {
        float m = rs[0] / (float)N_NODES;
        float v = rq[0] / (float)N_NODES - m * m;
        float sc = g[c] * rsqrtf(v + 1e-5f);
        ss[c] = sc;
        ss[36 + c] = be[c] - m * sc;
    }
}

// ---------------- final concat GEMM with BN folds ----------------

__global__ __launch_bounds__(256) void fused3_kernel(
    const float* __restrict__ X1, const float* __restrict__ ssA,
    const float* __restrict__ X2, const float* __restrict__ ssB,
    const float* __restrict__ X3, const float* __restrict__ ssC,
    const float* __restrict__ W, const float* __restrict__ b,
    float* __restrict__ out) {
    __shared__ float Wl[108 * 32];
    __shared__ float Al[64][109];
    int tid = threadIdx.x;
    for (int i = tid; i < 108 * 32; i += 256) Wl[i] = W[i];
    int r0 = blockIdx.x * 64;
    for (int i = tid; i < 64 * 108; i += 256) {
        int r = i / 108, f = i % 108;
        int row = r0 + r;
        float v = 0.f;
        if (row < N_NODES) {
            if (f < 36) {
                v = fmaxf(fmaf(ssA[f], X1[row * 36 + f], ssA[36 + f]), 0.f);
            } else if (f < 72) {
                int ff = f - 36;
                v = fmaxf(fmaf(ssB[ff], X2[row * 36 + ff], ssB[36 + ff]), 0.f);
            } else {
                int ff = f - 72;
                v = fmaf(ssC[ff], X3[row * 36 + ff], ssC[36 + ff]);
            }
        }
        Al[r][f] = v;
    }
    __syncthreads();
    int r = tid >> 2, q = tid & 3;
    int row = r0 + r;
    if (row >= N_NODES) return;
    float acc[8];
#pragma unroll
    for (int j = 0; j < 8; ++j) acc[j] = b[q * 8 + j];
    for (int f = 0; f < 108; ++f) {
        float a = Al[r][f];
#pragma unroll
        for (int j = 0; j < 8; ++j)
            acc[j] = fmaf(a, Wl[f * 32 + q * 8 + j], acc[j]);
    }
#pragma unroll
    for (int j = 0; j < 8; ++j) out[row * 32 + q * 8 + j] = acc[j];
}

// ---------------- launch ----------------

extern "C" void kernel_launch(void* const* d_in, const int* in_sizes, int n_in,
                              void* d_out, int out_size, void* d_ws, size_t ws_size,
                              hipStream_t stream) {
    const float* x      = (const float*)d_in[0];
    const int*   ei     = (const int*)d_in[1];
    const float* W1_1   = (const float*)d_in[2];
    // b1_1 / b1_2 cancel exactly under training-mode BN -> dropped.
    const float* g1_1   = (const float*)d_in[4];
    const float* be1_1  = (const float*)d_in[5];
    const float* W1_2   = (const float*)d_in[6];
    const float* g1_2   = (const float*)d_in[8];
    const float* be1_2  = (const float*)d_in[9];
    const float* gin_w1 = (const float*)d_in[10];
    const float* gin_b1 = (const float*)d_in[11];
    const float* gin_w2 = (const float*)d_in[12];
    const float* gin_b2 = (const float*)d_in[13];
    const float* g2     = (const float*)d_in[14];
    const float* be2    = (const float*)d_in[15];
    const float* W4     = (const float*)d_in[16];
    const float* b4     = (const float*)d_in[17];
    float* out = (float*)d_out;

    char* ws = (char*)d_ws;
    size_t off = 0;
    auto alloc = [&](size_t bytes) -> char* {
        char* p = ws + off;
        off = (off + bytes + 255) & ~(size_t)255;
        return p;
    };
    int*   cntD  = (int*)alloc((size_t)LCNT * 4);
    int*   cntS  = (int*)alloc((size_t)LCNT * 4);
    int*   bsum  = (int*)alloc(1024 * 4);
    int*   rp    = (int*)alloc((size_t)(N_NODES + 1) * 4);
    float* dis   = (float*)alloc((size_t)N_NODES * 4);
    int2*  edgepart = (int2*)alloc((size_t)N_EDGES * 8);
    int*   srcpart  = (int*)alloc((size_t)N_EDGES * 4);
    int2*  csrw  = (int2*)alloc((size_t)N_EDGES * 8);
    float* ssA   = (float*)alloc(72 * 4);
    float* ssB   = (float*)alloc(72 * 4);
    float* ssC   = (float*)alloc(72 * 4);
    float* partials = (float*)alloc((size_t)6250 * 72 * 4);
    constexpr size_t NB36 = (size_t)N_NODES * 36 * 4;      // f32 [N,36]
    constexpr size_t NBBF = (size_t)N_NODES * 128;         // bf16 [N,64] rows (128B)
    uint2* xbf = (uint2*)alloc(NBBF);
    uint2* R0  = (uint2*)alloc(NBBF);
    uint2* R1  = (uint2*)alloc(NBBF);
    uint2* R2  = (uint2*)alloc(NBBF);
    float* X1  = (float*)alloc(NB36);
    float* X2  = (float*)alloc(NB36);
    float* X3  = (float*)alloc(NB36);
    if (off > ws_size) return;

    // ---- preprocessing: counting-sort CSR build (no global atomics) ----
    part_count_kernel<<<NBLK, 256, 0, stream>>>(ei, cntD, cntS);
    scanA_kernel<<<SCAN_BLKS, 256, 0, stream>>>(cntD, cntD, bsum, LCNT);
    scanB_kernel<<<1, 1024, 0, stream>>>(bsum, SCAN_BLKS);
    scanC_kernel<<<SCAN_BLKS, 256, 0, stream>>>(cntD, bsum, LCNT);
    scanA_kernel<<<SCAN_BLKS, 256, 0, stream>>>(cntS, cntS, bsum, LCNT);
    scanB_kernel<<<1, 1024, 0, stream>>>(bsum, SCAN_BLKS);
    scanC_kernel<<<SCAN_BLKS, 256, 0, stream>>>(cntS, bsum, LCNT);
    part_scatter_kernel<<<NBLK, 256, 0, stream>>>(ei, cntD, cntS, edgepart, srcpart);
    deg_kernel<<<NBK, 256, 0, stream>>>(srcpart, cntS, dis);
    csr_kernel<<<NBK, 256, 0, stream>>>(edgepart, cntD, dis, rp, csrw);
    pack_x_kernel<<<(N_NODES * 16 + 255) / 256, 256, 0, stream>>>(x, xbf);

    const int STEP_BLKS = (N_NODES + 27) / 28;        // 3572
    const int GIN_BLKS  = (N_NODES + 15) / 16;        // 6250
    const int F3_BLKS   = (N_NODES + 63) / 64;        // 1563

    // ---- conv1_1 (Clenshaw, FI=64, A=x) ----
    cheb_step_kernel<64, 0, false, false, false, true><<<STEP_BLKS, 252, 0, stream>>>(
        rp, csrw, nullptr, nullptr, x, W1_1 + 7 * 2304, nullptr, R0, nullptr);
    cheb_step_kernel<64, 2, false, false, false, true><<<STEP_BLKS, 252, 0, stream>>>(
        rp, csrw, R0, nullptr, x, W1_1 + 6 * 2304, nullptr, R1, nullptr);
    cheb_step_kernel<64, 2, true, false, false, true><<<STEP_BLKS, 252, 0, stream>>>(
        rp, csrw, R1, R0, x, W1_1 + 5 * 2304, nullptr, R2, nullptr);
    cheb_step_kernel<64, 2, true, false, false, true><<<STEP_BLKS, 252, 0, stream>>>(
        rp, csrw, R2, R1, x, W1_1 + 4 * 2304, nullptr, R0, nullptr);
    cheb_step_kernel<64, 2, true, false, false, true><<<STEP_BLKS, 252, 0, stream>>>(
        rp, csrw, R0, R2, x, W1_1 + 3 * 2304, nullptr, R1, nullptr);
    cheb_step_kernel<64, 2, true, false, false, true><<<STEP_BLKS, 252, 0, stream>>>(
        rp, csrw, R1, R0, x, W1_1 + 2 * 2304, nullptr, R2, nullptr);
    cheb_step_kernel<64, 2, true, false, false, true><<<STEP_BLKS, 252, 0, stream>>>(
        rp, csrw, R2, R1, x, W1_1 + 1 * 2304, nullptr, R0, nullptr);
    cheb_step_kernel<64, 1, true, false, true, false><<<STEP_BLKS, 252, 0, stream>>>(
        rp, csrw, R0, R2, x, W1_1 + 0 * 2304, nullptr, X1, partials);
    finalize_kernel<<<36, 256, 0, stream>>>(partials, STEP_BLKS, g1_1, be1_1, ssA);

    // ---- conv1_2 (Clenshaw, FI=36, A=X1 with BN ssA) ----
    cheb_step_kernel<36, 0, false, true, false, true><<<STEP_BLKS, 252, 0, stream>>>(
        rp, csrw, nullptr, nullptr, X1, W1_2 + 7 * 1296, ssA, R0, nullptr);
    cheb_step_kernel<36, 2, false, true, false, true><<<STEP_BLKS, 252, 0, stream>>>(
        rp, csrw, R0, nullptr, X1, W1_2 + 6 * 1296, ssA, R1, nullptr);
    cheb_step_kernel<36, 2, true, true, false, true><<<STEP_BLKS, 252, 0, stream>>>(
        rp, csrw, R1, R0, X1, W1_2 + 5 * 1296, ssA, R2, nullptr);
    cheb_step_kernel<36, 2, true, true, false, true><<<STEP_BLKS, 252, 0, stream>>>(
        rp, csrw, R2, R1, X1, W1_2 + 4 * 1296, ssA, R0, nullptr);
    cheb_step_kernel<36, 2, true, true, false, true><<<STEP_BLKS, 252, 0, stream>>>(
        rp, csrw, R0, R2, X1, W1_2 + 3 * 1296, ssA, R1, nullptr);
    cheb_step_kernel<36, 2, true, true, false, true><<<STEP_BLKS, 252, 0, stream>>>(
        rp, csrw, R1, R0, X1, W1_2 + 2 * 1296, ssA, R2, nullptr);
    cheb_step_kernel<36, 2, true, true, false, true><<<STEP_BLKS, 252, 0, stream>>>(
        rp, csrw, R2, R1, X1, W1_2 + 1 * 1296, ssA, R0, nullptr);
    cheb_step_kernel<36, 1, true, true, true, false><<<STEP_BLKS, 252, 0, stream>>>(
        rp, csrw, R0, R2, X1, W1_2 + 0 * 1296, ssA, X2, partials);
    finalize_kernel<<<36, 256, 0, stream>>>(partials, STEP_BLKS, g1_2, be1_2, ssB);

    // ---- GIN ----
    gin_fused_kernel<<<GIN_BLKS, 256, 0, stream>>>(rp, csrw, xbf, gin_w1, gin_b1,
                                                   gin_w2, gin_b2, X3, partials);
    finalize_kernel<<<36, 256, 0, stream>>>(partials, GIN_BLKS, g2, be2, ssC);

    // ---- final concat GEMM ----
    fused3_kernel<<<F3_BLKS, 256, 0, stream>>>(X1, ssA, X2, ssB, X3, ssC, W4, b4, out);
}

// Round 8
// 970.741 us; speedup vs baseline: 1.7951x; 1.0196x over previous
//
#include <hip/hip_runtime.h>

constexpr int N_NODES = 100000;
constexpr int N_EDGES = 1600000;
constexpr int NBK  = 391;    // buckets of 256 nodes (node >> 8)
constexpr int NBLK = 640;    // partition blocks
constexpr int CHUNK = 2500;  // edges per block: 640*2500 = 1.6M exactly
constexpr int LCNT = NBK * NBLK;            // 250240
constexpr int SCAN_BLKS = (LCNT + 255) / 256;  // 978

// ---------------- bf16 helpers (RNE) ----------------

__device__ __forceinline__ unsigned bf16pack(float a, float b) {
    unsigned ua = __float_as_uint(a), ub = __float_as_uint(b);
    ua += 0x7fffu + ((ua >> 16) & 1u);
    ub += 0x7fffu + ((ub >> 16) & 1u);
    return (ua >> 16) | (ub & 0xffff0000u);
}
__device__ __forceinline__ float bflo(unsigned p) { return __uint_as_float(p << 16); }
__device__ __forceinline__ float bfhi(unsigned p) { return __uint_as_float(p & 0xffff0000u); }

// ---------------- preprocessing: atomic-free two-level counting sort ----------

__global__ __launch_bounds__(256) void part_count_kernel(
    const int* __restrict__ ei, int* __restrict__ cntD, int* __restrict__ cntS) {
    __shared__ int hd[NBK], hs[NBK];
    int tid = threadIdx.x;
    for (int i = tid; i < NBK; i += 256) { hd[i] = 0; hs[i] = 0; }
    __syncthreads();
    int e0 = blockIdx.x * CHUNK;
    for (int e = e0 + tid; e < e0 + CHUNK; e += 256) {
        int s = ei[e], d = ei[N_EDGES + e];
        atomicAdd(&hs[s >> 8], 1);
        atomicAdd(&hd[d >> 8], 1);
    }
    __syncthreads();
    for (int i = tid; i < NBK; i += 256) {
        cntD[i * NBLK + blockIdx.x] = hd[i];
        cntS[i * NBLK + blockIdx.x] = hs[i];
    }
}

__global__ __launch_bounds__(256) void scanA_kernel(const int* __restrict__ in,
                                                    int* __restrict__ out,
                                                    int* __restrict__ bsum, int L) {
    __shared__ int sm[256];
    int i = blockIdx.x * 256 + threadIdx.x;
    int v = (i < L) ? in[i] : 0;
    sm[threadIdx.x] = v;
    __syncthreads();
    for (int off = 1; off < 256; off <<= 1) {
        int t = (threadIdx.x >= off) ? sm[threadIdx.x - off] : 0;
        __syncthreads();
        sm[threadIdx.x] += t;
        __syncthreads();
    }
    if (i < L) out[i] = sm[threadIdx.x] - v;
    if (threadIdx.x == 255) bsum[blockIdx.x] = sm[255];
}

__global__ __launch_bounds__(1024) void scanB_kernel(int* __restrict__ bsum, int nb) {
    __shared__ int sm[1024];
    int t = threadIdx.x;
    int v = (t < nb) ? bsum[t] : 0;
    sm[t] = v;
    __syncthreads();
    for (int off = 1; off < 1024; off <<= 1) {
        int u = (t >= off) ? sm[t - off] : 0;
        __syncthreads();
        sm[t] += u;
        __syncthreads();
    }
    if (t < nb) bsum[t] = sm[t] - v;
}

__global__ __launch_bounds__(256) void scanC_kernel(int* __restrict__ out,
                                                    const int* __restrict__ bsum, int L) {
    int i = blockIdx.x * 256 + threadIdx.x;
    if (i < L) out[i] += bsum[blockIdx.x];
}

__global__ __launch_bounds__(256) void part_scatter_kernel(
    const int* __restrict__ ei, const int* __restrict__ scanD,
    const int* __restrict__ scanS, int2* __restrict__ edgepart,
    int* __restrict__ srcpart) {
    __shared__ int curD[NBK], curS[NBK];
    int tid = threadIdx.x;
    for (int i = tid; i < NBK; i += 256) {
        curD[i] = scanD[i * NBLK + blockIdx.x];
        curS[i] = scanS[i * NBLK + blockIdx.x];
    }
    __syncthreads();
    int e0 = blockIdx.x * CHUNK;
    for (int e = e0 + tid; e < e0 + CHUNK; e += 256) {
        int s = ei[e], d = ei[N_EDGES + e];
        int pd = atomicAdd(&curD[d >> 8], 1);
        edgepart[pd] = make_int2(s, d);
        int ps = atomicAdd(&curS[s >> 8], 1);
        srcpart[ps] = s;
    }
}

__global__ __launch_bounds__(256) void deg_kernel(const int* __restrict__ srcpart,
                                                  const int* __restrict__ scanS,
                                                  float* __restrict__ dis) {
    __shared__ int cnt[256];
    int b = blockIdx.x, tid = threadIdx.x;
    cnt[tid] = 0;
    __syncthreads();
    int beg = scanS[b * NBLK];
    int end = (b + 1 < NBK) ? scanS[(b + 1) * NBLK] : N_EDGES;
    for (int j = beg + tid; j < end; j += 256)
        atomicAdd(&cnt[srcpart[j] & 255], 1);
    __syncthreads();
    int node = b * 256 + tid;
    if (node < N_NODES) dis[node] = cnt[tid] > 0 ? rsqrtf((float)cnt[tid]) : 0.f;
}

__global__ __launch_bounds__(256) void csr_kernel(const int2* __restrict__ edgepart,
                                                  const int* __restrict__ scanD,
                                                  const float* __restrict__ dis,
                                                  int* __restrict__ rp,
                                                  int2* __restrict__ csrw) {
    __shared__ int cnt[256];
    __shared__ int lofs[256];
    __shared__ float disl[256];
    int b = blockIdx.x, tid = threadIdx.x;
    int beg = scanD[b * NBLK];
    int end = (b + 1 < NBK) ? scanD[(b + 1) * NBLK] : N_EDGES;
    int node = b * 256 + tid;
    cnt[tid] = 0;
    disl[tid] = (node < N_NODES) ? dis[node] : 0.f;
    __syncthreads();
    for (int j = beg + tid; j < end; j += 256)
        atomicAdd(&cnt[edgepart[j].y & 255], 1);
    __syncthreads();
    int v = cnt[tid];
    lofs[tid] = v;
    __syncthreads();
    for (int off = 1; off < 256; off <<= 1) {
        int t = (tid >= off) ? lofs[tid - off] : 0;
        __syncthreads();
        lofs[tid] += t;
        __syncthreads();
    }
    int myexc = lofs[tid] - v;
    if (node < N_NODES) rp[node] = beg + myexc;
    if (b == NBK - 1 && tid == 0) rp[N_NODES] = N_EDGES;
    __syncthreads();
    lofs[tid] = myexc;
    cnt[tid] = 0;
    __syncthreads();
    for (int j = beg + tid; j < end; j += 256) {
        int2 e = edgepart[j];
        int dl = e.y & 255;
        int pos = beg + lofs[dl] + atomicAdd(&cnt[dl], 1);
        csrw[pos] = make_int2(e.x, __float_as_int(-dis[e.x] * disl[dl]));
    }
}

// ---------------- fused Clenshaw step ----------------
// OUT[row] = SCALE * sum_j w_j*INb[src_j] + A'[row]@W - (HAS_B2 ? B2b[row] : 0)
// INb/B2b bf16 packed rows: 9 uint2 = 72B (8B-aligned). SCALE==0 -> projection only.

template <int FI, int SCALE, bool HAS_B2, bool BN_A, bool FUSE_STATS, bool OUT_BF16>
__global__ __launch_bounds__(256) void cheb_step_kernel(
    const int* __restrict__ rp, const int2* __restrict__ csrw,
    const uint2* __restrict__ INb, const uint2* __restrict__ B2b,
    const float* __restrict__ A, const float* __restrict__ W,
    const float* __restrict__ ss, void* __restrict__ OUT,
    float* __restrict__ partials) {
    __shared__ float Wl[FI * 36];
    __shared__ float Atile[28][FI + 1];
    __shared__ float ls[72];
    int tid = threadIdx.x;                       // 252 threads = 28 rows x 9 lanes
    for (int i = tid; i < FI * 36; i += 252) Wl[i] = W[i];
    int r0 = blockIdx.x * 28;
    for (int i = tid; i < 28 * FI; i += 252) {
        int r = i / FI, f = i % FI;
        int row = r0 + r;
        float v = (row < N_NODES) ? A[row * FI + f] : 0.f;
        if (BN_A) v = fmaxf(fmaf(ss[f], v, ss[36 + f]), 0.f);
        Atile[r][f] = v;
    }
    if (FUSE_STATS && tid < 72) ls[tid] = 0.f;
    __syncthreads();
    int r = tid / 9, c = tid % 9;
    int row = r0 + r;
    bool valid = row < N_NODES;
    float ax = 0, ay = 0, az = 0, aw = 0;
    float bx = 0, by = 0, bz = 0, bw = 0;
    float cx = 0, cy = 0, cz = 0, cw = 0;
    float dx = 0, dy = 0, dz = 0, dw = 0;
    if (SCALE != 0 && valid) {
        int beg = rp[row], end = rp[row + 1];
        int j = beg;
        for (; j + 7 < end; j += 8) {
            int2 e0 = csrw[j],     e1 = csrw[j + 1], e2 = csrw[j + 2], e3 = csrw[j + 3];
            int2 e4 = csrw[j + 4], e5 = csrw[j + 5], e6 = csrw[j + 6], e7 = csrw[j + 7];
            uint2 u0 = INb[e0.x * 9 + c];
            uint2 u1 = INb[e1.x * 9 + c];
            uint2 u2 = INb[e2.x * 9 + c];
            uint2 u3 = INb[e3.x * 9 + c];
            uint2 u4 = INb[e4.x * 9 + c];
            uint2 u5 = INb[e5.x * 9 + c];
            uint2 u6 = INb[e6.x * 9 + c];
            uint2 u7 = INb[e7.x * 9 + c];
            float w0 = __int_as_float(e0.y), w1 = __int_as_float(e1.y);
            float w2 = __int_as_float(e2.y), w3 = __int_as_float(e3.y);
            float w4 = __int_as_float(e4.y), w5 = __int_as_float(e5.y);
            float w6 = __int_as_float(e6.y), w7 = __int_as_float(e7.y);
            ax = fmaf(w0, bflo(u0.x), ax); ay = fmaf(w0, bfhi(u0.x), ay);
            az = fmaf(w0, bflo(u0.y), az); aw = fmaf(w0, bfhi(u0.y), aw);
            bx = fmaf(w1, bflo(u1.x), bx); by = fmaf(w1, bfhi(u1.x), by);
            bz = fmaf(w1, bflo(u1.y), bz); bw = fmaf(w1, bfhi(u1.y), bw);
            cx = fmaf(w2, bflo(u2.x), cx); cy = fmaf(w2, bfhi(u2.x), cy);
            cz = fmaf(w2, bflo(u2.y), cz); cw = fmaf(w2, bfhi(u2.y), cw);
            dx = fmaf(w3, bflo(u3.x), dx); dy = fmaf(w3, bfhi(u3.x), dy);
            dz = fmaf(w3, bflo(u3.y), dz); dw = fmaf(w3, bfhi(u3.y), dw);
            ax = fmaf(w4, bflo(u4.x), ax); ay = fmaf(w4, bfhi(u4.x), ay);
            az = fmaf(w4, bflo(u4.y), az); aw = fmaf(w4, bfhi(u4.y), aw);
            bx = fmaf(w5, bflo(u5.x), bx); by = fmaf(w5, bfhi(u5.x), by);
            bz = fmaf(w5, bflo(u5.y), bz); bw = fmaf(w5, bfhi(u5.y), bw);
            cx = fmaf(w6, bflo(u6.x), cx); cy = fmaf(w6, bfhi(u6.x), cy);
            cz = fmaf(w6, bflo(u6.y), cz); cw = fmaf(w6, bfhi(u6.y), cw);
            dx = fmaf(w7, bflo(u7.x), dx); dy = fmaf(w7, bfhi(u7.x), dy);
            dz = fmaf(w7, bflo(u7.y), dz); dw = fmaf(w7, bfhi(u7.y), dw);
        }
        for (; j + 3 < end; j += 4) {
            int2 e0 = csrw[j], e1 = csrw[j + 1], e2 = csrw[j + 2], e3 = csrw[j + 3];
            uint2 u0 = INb[e0.x * 9 + c];
            uint2 u1 = INb[e1.x * 9 + c];
            uint2 u2 = INb[e2.x * 9 + c];
            uint2 u3 = INb[e3.x * 9 + c];
            float w0 = __int_as_float(e0.y), w1 = __int_as_float(e1.y);
            float w2 = __int_as_float(e2.y), w3 = __int_as_float(e3.y);
            ax = fmaf(w0, bflo(u0.x), ax); ay = fmaf(w0, bfhi(u0.x), ay);
            az = fmaf(w0, bflo(u0.y), az); aw = fmaf(w0, bfhi(u0.y), aw);
            bx = fmaf(w1, bflo(u1.x), bx); by = fmaf(w1, bfhi(u1.x), by);
            bz = fmaf(w1, bflo(u1.y), bz); bw = fmaf(w1, bfhi(u1.y), bw);
            cx = fmaf(w2, bflo(u2.x), cx); cy = fmaf(w2, bfhi(u2.x), cy);
            cz = fmaf(w2, bflo(u2.y), cz); cw = fmaf(w2, bfhi(u2.y), cw);
            dx = fmaf(w3, bflo(u3.x), dx); dy = fmaf(w3, bfhi(u3.x), dy);
            dz = fmaf(w3, bflo(u3.y), dz); dw = fmaf(w3, bfhi(u3.y), dw);
        }
        for (; j < end; ++j) {
            int2 e = csrw[j];
            uint2 u = INb[e.x * 9 + c];
            float w = __int_as_float(e.y);
            ax = fmaf(w, bflo(u.x), ax); ay = fmaf(w, bfhi(u.x), ay);
            az = fmaf(w, bflo(u.y), az); aw = fmaf(w, bfhi(u.y), aw);
        }
        ax += bx + cx + dx; ay += by + cy + dy;
        az += bz + cz + dz; aw += bw + cw + dw;
    }
    float px = 0, py = 0, pz = 0, pw = 0;
    const float4* Wl4 = (const float4*)Wl;
#pragma unroll 4
    for (int f = 0; f < FI; ++f) {
        float a = Atile[r][f];
        float4 wv = Wl4[f * 9 + c];
        px = fmaf(a, wv.x, px); py = fmaf(a, wv.y, py);
        pz = fmaf(a, wv.z, pz); pw = fmaf(a, wv.w, pw);
    }
    const float S = (float)SCALE;
    float4 o;
    o.x = fmaf(S, ax, px); o.y = fmaf(S, ay, py);
    o.z = fmaf(S, az, pz); o.w = fmaf(S, aw, pw);
    if (valid) {
        if (HAS_B2) {
            uint2 u = B2b[row * 9 + c];
            o.x -= bflo(u.x); o.y -= bfhi(u.x);
            o.z -= bflo(u.y); o.w -= bfhi(u.y);
        }
        if (OUT_BF16) {
            ((uint2*)OUT)[row * 9 + c] =
                make_uint2(bf16pack(o.x, o.y), bf16pack(o.z, o.w));
        } else {
            ((float4*)OUT)[row * 9 + c] = o;
        }
        if (FUSE_STATS) {
            atomicAdd(&ls[c * 4 + 0], o.x); atomicAdd(&ls[36 + c * 4 + 0], o.x * o.x);
            atomicAdd(&ls[c * 4 + 1], o.y); atomicAdd(&ls[36 + c * 4 + 1], o.y * o.y);
            atomicAdd(&ls[c * 4 + 2], o.z); atomicAdd(&ls[36 + c * 4 + 2], o.z * o.z);
            atomicAdd(&ls[c * 4 + 3], o.w); atomicAdd(&ls[36 + c * 4 + 3], o.w * o.w);
        }
    }
    if (FUSE_STATS) {
        __syncthreads();
        if (tid < 72) partials[blockIdx.x * 72 + tid] = ls[tid];
    }
}

// ---------------- GIN gather (projection-first) ----------------
// m1 = relu(y[row] + sum y[src] + b1); OUT = relu(m1 @ w2 + b2); + stats.
// y is bf16 packed 72B rows.

__global__ __launch_bounds__(256) void gin_gather_kernel(
    const int* __restrict__ rp, const int2* __restrict__ csrw,
    const uint2* __restrict__ Yb, const float* __restrict__ b1,
    const float* __restrict__ w2, const float* __restrict__ b2,
    float* __restrict__ OUT, float* __restrict__ partials) {
    __shared__ float W2l[36 * 36];
    __shared__ float B1l[36], B2l[36];
    __shared__ float M1t[28][37];
    __shared__ float ls[72];
    int tid = threadIdx.x;                       // 252 = 28 rows x 9 lanes
    for (int i = tid; i < 36 * 36; i += 252) W2l[i] = w2[i];
    if (tid < 36) { B1l[tid] = b1[tid]; B2l[tid] = b2[tid]; }
    if (tid < 72) ls[tid] = 0.f;
    __syncthreads();
    int r = tid / 9, c = tid % 9;
    int row = blockIdx.x * 28 + r;
    bool valid = row < N_NODES;
    float ax = 0, ay = 0, az = 0, aw = 0;
    float bx = 0, by = 0, bz = 0, bw = 0;
    float cx = 0, cy = 0, cz = 0, cw = 0;
    float dx = 0, dy = 0, dz = 0, dw = 0;
    if (valid) {
        uint2 us = Yb[row * 9 + c];
        ax = bflo(us.x); ay = bfhi(us.x); az = bflo(us.y); aw = bfhi(us.y);
        int beg = rp[row], end = rp[row + 1];
        int j = beg;
        for (; j + 7 < end; j += 8) {
            int s0 = csrw[j].x,     s1 = csrw[j + 1].x, s2 = csrw[j + 2].x, s3 = csrw[j + 3].x;
            int s4 = csrw[j + 4].x, s5 = csrw[j + 5].x, s6 = csrw[j + 6].x, s7 = csrw[j + 7].x;
            uint2 u0 = Yb[s0 * 9 + c];
            uint2 u1 = Yb[s1 * 9 + c];
            uint2 u2 = Yb[s2 * 9 + c];
            uint2 u3 = Yb[s3 * 9 + c];
            uint2 u4 = Yb[s4 * 9 + c];
            uint2 u5 = Yb[s5 * 9 + c];
            uint2 u6 = Yb[s6 * 9 + c];
            uint2 u7 = Yb[s7 * 9 + c];
            ax += bflo(u0.x) + bflo(u4.x); ay += bfhi(u0.x) + bfhi(u4.x);
            az += bflo(u0.y) + bflo(u4.y); aw += bfhi(u0.y) + bfhi(u4.y);
            bx += bflo(u1.x) + bflo(u5.x); by += bfhi(u1.x) + bfhi(u5.x);
            bz += bflo(u1.y) + bflo(u5.y); bw += bfhi(u1.y) + bfhi(u5.y);
            cx += bflo(u2.x) + bflo(u6.x); cy += bfhi(u2.x) + bfhi(u6.x);
            cz += bflo(u2.y) + bflo(u6.y); cw += bfhi(u2.y) + bfhi(u6.y);
            dx += bflo(u3.x) + bflo(u7.x); dy += bfhi(u3.x) + bfhi(u7.x);
            dz += bflo(u3.y) + bflo(u7.y); dw += bfhi(u3.y) + bfhi(u7.y);
        }
        for (; j + 3 < end; j += 4) {
            int s0 = csrw[j].x, s1 = csrw[j + 1].x, s2 = csrw[j + 2].x, s3 = csrw[j + 3].x;
            uint2 u0 = Yb[s0 * 9 + c];
            uint2 u1 = Yb[s1 * 9 + c];
            uint2 u2 = Yb[s2 * 9 + c];
            uint2 u3 = Yb[s3 * 9 + c];
            ax += bflo(u0.x); ay += bfhi(u0.x); az += bflo(u0.y); aw += bfhi(u0.y);
            bx += bflo(u1.x); by += bfhi(u1.x); bz += bflo(u1.y); bw += bfhi(u1.y);
            cx += bflo(u2.x); cy += bfhi(u2.x); cz += bflo(u2.y); cw += bfhi(u2.y);
            dx += bflo(u3.x); dy += bfhi(u3.x); dz += bflo(u3.y); dw += bfhi(u3.y);
        }
        for (; j < end; ++j) {
            uint2 u = Yb[csrw[j].x * 9 + c];
            ax += bflo(u.x); ay += bfhi(u.x);
            az += bflo(u.y); aw += bfhi(u.y);
        }
        ax += bx + cx + dx; ay += by + cy + dy;
        az += bz + cz + dz; aw += bw + cw + dw;
    }
    float m0 = fmaxf(ax + B1l[c * 4 + 0], 0.f);
    float m1 = fmaxf(ay + B1l[c * 4 + 1], 0.f);
    float m2 = fmaxf(az + B1l[c * 4 + 2], 0.f);
    float m3 = fmaxf(aw + B1l[c * 4 + 3], 0.f);
    M1t[r][c * 4 + 0] = m0; M1t[r][c * 4 + 1] = m1;
    M1t[r][c * 4 + 2] = m2; M1t[r][c * 4 + 3] = m3;
    __syncthreads();
    float o0 = B2l[c * 4 + 0], o1 = B2l[c * 4 + 1];
    float o2 = B2l[c * 4 + 2], o3 = B2l[c * 4 + 3];
    const float4* W2l4 = (const float4*)W2l;
#pragma unroll 4
    for (int f = 0; f < 36; ++f) {
        float a = M1t[r][f];
        float4 wv = W2l4[f * 9 + c];
        o0 = fmaf(a, wv.x, o0); o1 = fmaf(a, wv.y, o1);
        o2 = fmaf(a, wv.z, o2); o3 = fmaf(a, wv.w, o3);
    }
    o0 = fmaxf(o0, 0.f); o1 = fmaxf(o1, 0.f);
    o2 = fmaxf(o2, 0.f); o3 = fmaxf(o3, 0.f);
    if (valid) {
        float4 o = {o0, o1, o2, o3};
        ((float4*)OUT)[row * 9 + c] = o;
        atomicAdd(&ls[c * 4 + 0], o0); atomicAdd(&ls[36 + c * 4 + 0], o0 * o0);
        atomicAdd(&ls[c * 4 + 1], o1); atomicAdd(&ls[36 + c * 4 + 1], o1 * o1);
        atomicAdd(&ls[c * 4 + 2], o2); atomicAdd(&ls[36 + c * 4 + 2], o2 * o2);
        atomicAdd(&ls[c * 4 + 3], o3); atomicAdd(&ls[36 + c * 4 + 3], o3 * o3);
    }
    __syncthreads();
    if (tid < 72) partials[blockIdx.x * 72 + tid] = ls[tid];
}

// ---------------- finalize: reduce partials -> BN scale/shift ----------------

__global__ __launch_bounds__(256) void finalize_kernel(
    const float* __restrict__ partials, int nb, const float* __restrict__ g,
    const float* __restrict__ be, float* __restrict__ ss) {
    __shared__ float rs[256], rq[256];
    int c = blockIdx.x;
    int t = threadIdx.x;
    float s = 0.f, q = 0.f;
    for (int i = t; i < nb; i += 256) {
        s += partials[i * 72 + c];
        q += partials[i * 72 + c + 36];
    }
    rs[t] = s; rq[t] = q;
    __syncthreads();
    for (int off = 128; off > 0; off >>= 1) {
        if (t < off) { rs[t] += rs[t + off]; rq[t] += rq[t + off]; }
        __syncthreads();
    }
    if (t == 0) {
        float m = rs[0] / (float)N_NODES;
        float v = rq[0] / (float)N_NODES - m * m;
        float sc = g[c] * rsqrtf(v + 1e-5f);
        ss[c] = sc;
        ss[36 + c] = be[c] - m * sc;
    }
}

// ---------------- final concat GEMM with BN folds ----------------

__global__ __launch_bounds__(256) void fused3_kernel(
    const float* __restrict__ X1, const float* __restrict__ ssA,
    const float* __restrict__ X2, const float* __restrict__ ssB,
    const float* __restrict__ X3, const float* __restrict__ ssC,
    const float* __restrict__ W, const float* __restrict__ b,
    float* __restrict__ out) {
    __shared__ float Wl[108 * 32];
    __shared__ float Al[64][109];
    int tid = threadIdx.x;
    for (int i = tid; i < 108 * 32; i += 256) Wl[i] = W[i];
    int r0 = blockIdx.x * 64;
    for (int i = tid; i < 64 * 108; i += 256) {
        int r = i / 108, f = i % 108;
        int row = r0 + r;
        float v = 0.f;
        if (row < N_NODES) {
            if (f < 36) {
                v = fmaxf(fmaf(ssA[f], X1[row * 36 + f], ssA[36 + f]), 0.f);
            } else if (f < 72) {
                int ff = f - 36;
                v = fmaxf(fmaf(ssB[ff], X2[row * 36 + ff], ssB[36 + ff]), 0.f);
            } else {
                int ff = f - 72;
                v = fmaf(ssC[ff], X3[row * 36 + ff], ssC[36 + ff]);
            }
        }
        Al[r][f] = v;
    }
    __syncthreads();
    int r = tid >> 2, q = tid & 3;
    int row = r0 + r;
    if (row >= N_NODES) return;
    float acc[8];
#pragma unroll
    for (int j = 0; j < 8; ++j) acc[j] = b[q * 8 + j];
    for (int f = 0; f < 108; ++f) {
        float a = Al[r][f];
#pragma unroll
        for (int j = 0; j < 8; ++j)
            acc[j] = fmaf(a, Wl[f * 32 + q * 8 + j], acc[j]);
    }
#pragma unroll
    for (int j = 0; j < 8; ++j) out[row * 32 + q * 8 + j] = acc[j];
}

// ---------------- launch ----------------

extern "C" void kernel_launch(void* const* d_in, const int* in_sizes, int n_in,
                              void* d_out, int out_size, void* d_ws, size_t ws_size,
                              hipStream_t stream) {
    const float* x      = (const float*)d_in[0];
    const int*   ei     = (const int*)d_in[1];
    const float* W1_1   = (const float*)d_in[2];
    // b1_1 / b1_2 cancel exactly under training-mode BN -> dropped.
    const float* g1_1   = (const float*)d_in[4];
    const float* be1_1  = (const float*)d_in[5];
    const float* W1_2   = (const float*)d_in[6];
    const float* g1_2   = (const float*)d_in[8];
    const float* be1_2  = (const float*)d_in[9];
    const float* gin_w1 = (const float*)d_in[10];
    const float* gin_b1 = (const float*)d_in[11];
    const float* gin_w2 = (const float*)d_in[12];
    const float* gin_b2 = (const float*)d_in[13];
    const float* g2     = (const float*)d_in[14];
    const float* be2    = (const float*)d_in[15];
    const float* W4     = (const float*)d_in[16];
    const float* b4     = (const float*)d_in[17];
    float* out = (float*)d_out;

    char* ws = (char*)d_ws;
    size_t off = 0;
    auto alloc = [&](size_t bytes) -> char* {
        char* p = ws + off;
        off = (off + bytes + 255) & ~(size_t)255;
        return p;
    };
    int*   cntD  = (int*)alloc((size_t)LCNT * 4);
    int*   cntS  = (int*)alloc((size_t)LCNT * 4);
    int*   bsum  = (int*)alloc(1024 * 4);
    int*   rp    = (int*)alloc((size_t)(N_NODES + 1) * 4);
    float* dis   = (float*)alloc((size_t)N_NODES * 4);
    int2*  edgepart = (int2*)alloc((size_t)N_EDGES * 8);
    int*   srcpart  = (int*)alloc((size_t)N_EDGES * 4);
    int2*  csrw  = (int2*)alloc((size_t)N_EDGES * 8);
    float* ssA   = (float*)alloc(72 * 4);
    float* ssB   = (float*)alloc(72 * 4);
    float* ssC   = (float*)alloc(72 * 4);
    float* partials = (float*)alloc((size_t)6250 * 72 * 4);
    constexpr size_t NB36 = (size_t)N_NODES * 36 * 4;      // f32 [N,36]
    constexpr size_t NBBF = (size_t)N_NODES * 72;          // bf16 packed 72B rows
    uint2* R0  = (uint2*)alloc(NBBF);
    uint2* R1  = (uint2*)alloc(NBBF);
    uint2* R2  = (uint2*)alloc(NBBF);
    float* X1  = (float*)alloc(NB36);
    float* X2  = (float*)alloc(NB36);
    float* X3  = (float*)alloc(NB36);
    if (off > ws_size) return;

    // ---- preprocessing: counting-sort CSR build (no global atomics) ----
    part_count_kernel<<<NBLK, 256, 0, stream>>>(ei, cntD, cntS);
    scanA_kernel<<<SCAN_BLKS, 256, 0, stream>>>(cntD, cntD, bsum, LCNT);
    scanB_kernel<<<1, 1024, 0, stream>>>(bsum, SCAN_BLKS);
    scanC_kernel<<<SCAN_BLKS, 256, 0, stream>>>(cntD, bsum, LCNT);
    scanA_kernel<<<SCAN_BLKS, 256, 0, stream>>>(cntS, cntS, bsum, LCNT);
    scanB_kernel<<<1, 1024, 0, stream>>>(bsum, SCAN_BLKS);
    scanC_kernel<<<SCAN_BLKS, 256, 0, stream>>>(cntS, bsum, LCNT);
    part_scatter_kernel<<<NBLK, 256, 0, stream>>>(ei, cntD, cntS, edgepart, srcpart);
    deg_kernel<<<NBK, 256, 0, stream>>>(srcpart, cntS, dis);
    csr_kernel<<<NBK, 256, 0, stream>>>(edgepart, cntD, dis, rp, csrw);

    const int STEP_BLKS = (N_NODES + 27) / 28;        // 3572
    const int F3_BLKS   = (N_NODES + 63) / 64;        // 1563

    // ---- conv1_1 (Clenshaw, FI=64, A=x) ----
    cheb_step_kernel<64, 0, false, false, false, true><<<STEP_BLKS, 252, 0, stream>>>(
        rp, csrw, nullptr, nullptr, x, W1_1 + 7 * 2304, nullptr, R0, nullptr);
    cheb_step_kernel<64, 2, false, false, false, true><<<STEP_BLKS, 252, 0, stream>>>(
        rp, csrw, R0, nullptr, x, W1_1 + 6 * 2304, nullptr, R1, nullptr);
    cheb_step_kernel<64, 2, true, false, false, true><<<STEP_BLKS, 252, 0, stream>>>(
        rp, csrw, R1, R0, x, W1_1 + 5 * 2304, nullptr, R2, nullptr);
    cheb_step_kernel<64, 2, true, false, false, true><<<STEP_BLKS, 252, 0, stream>>>(
        rp, csrw, R2, R1, x, W1_1 + 4 * 2304, nullptr, R0, nullptr);
    cheb_step_kernel<64, 2, true, false, false, true><<<STEP_BLKS, 252, 0, stream>>>(
        rp, csrw, R0, R2, x, W1_1 + 3 * 2304, nullptr, R1, nullptr);
    cheb_step_kernel<64, 2, true, false, false, true><<<STEP_BLKS, 252, 0, stream>>>(
        rp, csrw, R1, R0, x, W1_1 + 2 * 2304, nullptr, R2, nullptr);
    cheb_step_kernel<64, 2, true, false, false, true><<<STEP_BLKS, 252, 0, stream>>>(
        rp, csrw, R2, R1, x, W1_1 + 1 * 2304, nullptr, R0, nullptr);
    cheb_step_kernel<64, 1, true, false, true, false><<<STEP_BLKS, 252, 0, stream>>>(
        rp, csrw, R0, R2, x, W1_1 + 0 * 2304, nullptr, X1, partials);
    finalize_kernel<<<36, 256, 0, stream>>>(partials, STEP_BLKS, g1_1, be1_1, ssA);

    // ---- conv1_2 (Clenshaw, FI=36, A=X1 with BN ssA) ----
    cheb_step_kernel<36, 0, false, true, false, true><<<STEP_BLKS, 252, 0, stream>>>(
        rp, csrw, nullptr, nullptr, X1, W1_2 + 7 * 1296, ssA, R0, nullptr);
    cheb_step_kernel<36, 2, false, true, false, true><<<STEP_BLKS, 252, 0, stream>>>(
        rp, csrw, R0, nullptr, X1, W1_2 + 6 * 1296, ssA, R1, nullptr);
    cheb_step_kernel<36, 2, true, true, false, true><<<STEP_BLKS, 252, 0, stream>>>(
        rp, csrw, R1, R0, X1, W1_2 + 5 * 1296, ssA, R2, nullptr);
    cheb_step_kernel<36, 2, true, true, false, true><<<STEP_BLKS, 252, 0, stream>>>(
        rp, csrw, R2, R1, X1, W1_2 + 4 * 1296, ssA, R0, nullptr);
    cheb_step_kernel<36, 2, true, true, false, true><<<STEP_BLKS, 252, 0, stream>>>(
        rp, csrw, R0, R2, X1, W1_2 + 3 * 1296, ssA, R1, nullptr);
    cheb_step_kernel<36, 2, true, true, false, true><<<STEP_BLKS, 252, 0, stream>>>(
        rp, csrw, R1, R0, X1, W1_2 + 2 * 1296, ssA, R2, nullptr);
    cheb_step_kernel<36, 2, true, true, false, true><<<STEP_BLKS, 252, 0, stream>>>(
        rp, csrw, R2, R1, X1, W1_2 + 1 * 1296, ssA, R0, nullptr);
    cheb_step_kernel<36, 1, true, true, true, false><<<STEP_BLKS, 252, 0, stream>>>(
        rp, csrw, R0, R2, X1, W1_2 + 0 * 1296, ssA, X2, partials);
    finalize_kernel<<<36, 256, 0, stream>>>(partials, STEP_BLKS, g1_2, be1_2, ssB);

    // ---- GIN (projection-first: y = x@gin_w1, then 36-wide gather) ----
    cheb_step_kernel<64, 0, false, false, false, true><<<STEP_BLKS, 252, 0, stream>>>(
        rp, csrw, nullptr, nullptr, x, gin_w1, nullptr, R0, nullptr);
    gin_gather_kernel<<<STEP_BLKS, 252, 0, stream>>>(rp, csrw, R0, gin_b1,
                                                     gin_w2, gin_b2, X3, partials);
    finalize_kernel<<<36, 256, 0, stream>>>(partials, STEP_BLKS, g2, be2, ssC);

    // ---- final concat GEMM ----
    fused3_kernel<<<F3_BLKS, 256, 0, stream>>>(X1, ssA, X2, ssB, X3, ssC, W4, b4, out);
}